// Round 9
// baseline (203.839 us; speedup 1.0000x reference)
//
#include <hip/hip_runtime.h>
#include <hip/hip_bf16.h>
#include <stdint.h>

#define NTOK 8192
#define DIN  256
#define DOUT 256
#define NEXP 16
#define HID  512
#define NKA  (NTOK*2)    // total assignments
#define NBLK (NTOK/256)  // routing/fill blocks (256 tokens each)
#define MAXTILE 272      // sum ceil(Te/64) <= 16384/64 + 16
#define GK 768           // gate split-GEMM K: [x_hi | x_lo | x_hi]

typedef __bf16 bf16x8 __attribute__((ext_vector_type(8)));
typedef __bf16 bf16x4 __attribute__((ext_vector_type(4)));
typedef float  f32x4  __attribute__((ext_vector_type(4)));

// async 16B global -> LDS (DMA; wave-uniform LDS base + lane*16)
__device__ __forceinline__ void async_cp16(const __bf16* g, __bf16* l) {
  __builtin_amdgcn_global_load_lds(
      (const __attribute__((address_space(1))) unsigned int*)g,
      (__attribute__((address_space(3))) unsigned int*)l, 16, 0, 0);
}

// ------ fused prep: cvt_x(split) + gate_w_split + 3x transpose_cvt + zero(logits) ------
__device__ __forceinline__ void transpose_cvt_body(const float* __restrict__ src,
                                                   __bf16* __restrict__ dst,
                                                   int K, int N, int bx, int by, int bz,
                                                   int tx, int ty, float (*t)[33]) {
  int e = bz, k0 = bx * 32, n0 = by * 32;
  #pragma unroll
  for (int j = 0; j < 4; j++) {
    int kl = ty + j * 8;
    t[kl][tx] = src[(size_t)(k0 + kl) * (NEXP * N) + (size_t)e * N + n0 + tx];
  }
  __syncthreads();
  #pragma unroll
  for (int j = 0; j < 4; j++) {
    int nl = ty + j * 8;
    dst[(size_t)e * N * K + (size_t)(n0 + nl) * K + k0 + tx] = (__bf16)t[tx][nl];
  }
}

__global__ __launch_bounds__(256) void prep_kernel(
    const float* __restrict__ x, __bf16* __restrict__ xs,
    const float* __restrict__ gw, __bf16* __restrict__ gwt,
    const float* __restrict__ w1, __bf16* __restrict__ w1t,
    const float* __restrict__ w2, __bf16* __restrict__ w2t,
    const float* __restrict__ w3, __bf16* __restrict__ w3t,
    int* __restrict__ gtile_e, int* __restrict__ gtile_mt,
    int* __restrict__ gntiles, int* __restrict__ gseg,
    float* __restrict__ logitz) {
  __shared__ float t[32][33];
  int idx = blockIdx.x;
  int tid = threadIdx.x;
  int tx = tid & 31, ty = tid >> 5;
  if (idx < 2048) {
    // cvt_x: fp32 -> bf16x2 split rows [hi | lo | hi]  (hi block doubles as GEMM1 input)
    int i = idx * 256 + tid;
    float4 v = ((const float4*)x)[i];
    int base = i * 4;
    int tk = base >> 8, c = base & 255;
    bf16x4 hi = { (__bf16)v.x, (__bf16)v.y, (__bf16)v.z, (__bf16)v.w };
    bf16x4 lo = { (__bf16)(v.x - (float)hi[0]), (__bf16)(v.y - (float)hi[1]),
                  (__bf16)(v.z - (float)hi[2]), (__bf16)(v.w - (float)hi[3]) };
    __bf16* row = xs + (size_t)tk * GK + c;
    *(bf16x4*)(row)       = hi;
    *(bf16x4*)(row + 256) = lo;
    *(bf16x4*)(row + 512) = hi;
  } else if (idx < 2176) {
    // gate weight: transpose + bf16x2 split into B^T layout [n][GK]
    int g = idx - 2048;
    int k0 = (g & 7) * 32, n0 = (g >> 3) * 32;
    #pragma unroll
    for (int j = 0; j < 4; j++) {
      int kl = ty + j * 8;
      t[kl][tx] = gw[(size_t)(k0 + kl) * HID + n0 + tx];
    }
    __syncthreads();
    #pragma unroll
    for (int j = 0; j < 4; j++) {
      int nl = ty + j * 8;
      float v = t[tx][nl];
      __bf16 hi = (__bf16)v;
      __bf16 lo = (__bf16)(v - (float)hi);
      __bf16* drow = gwt + (size_t)(n0 + nl) * GK + k0 + tx;
      drow[0]   = hi;
      drow[256] = hi;
      drow[512] = lo;
    }
    if (g == 0) {
      if (tid < 128) { gtile_e[tid] = 0; gtile_mt[tid] = tid; }
      else if (tid == 128) { *gntiles = 128; }
      else if (tid == 129) { gseg[0] = 0; gseg[1] = NTOK; }
    }
  } else if (idx < 4224) {
    int g = idx - 2176;  // w1: K=256 (8), N=512 (16), E=16
    transpose_cvt_body(w1, w1t, DIN, HID, g & 7, (g >> 3) & 15, g >> 7, tx, ty, t);
  } else if (idx < 8320) {
    int g = idx - 4224;  // w2: K=512 (16), N=512 (16), E=16
    transpose_cvt_body(w2, w2t, HID, HID, g & 15, (g >> 4) & 15, g >> 8, tx, ty, t);
  } else if (idx < 10368) {
    int g = idx - 8320;  // w3: K=512 (16), N=256 (8), E=16
    transpose_cvt_body(w3, w3t, HID, DOUT, g & 15, (g >> 4) & 7, g >> 7, tx, ty, t);
  } else {
    // zero the logits accumulator (gate GEMM combines partials via atomicAdd)
    int i = (idx - 10368) * 256 + tid;
    ((float4*)logitz)[i] = make_float4(0.f, 0.f, 0.f, 0.f);
  }
}

// ---------------- top-2 + softmax + block-local histogram/ranks ----------------
__global__ __launch_bounds__(256) void top2_kernel(const float* __restrict__ logits,
                                                   const float* __restrict__ gb,
                                                   int2* __restrict__ e01,
                                                   float2* __restrict__ g01,
                                                   int* __restrict__ lrank,
                                                   int* __restrict__ blockhist) {
  __shared__ int hist[NEXP];
  __shared__ float gbl[NEXP];
  int tid = threadIdx.x;
  if (tid < NEXP) { hist[tid] = 0; gbl[tid] = gb[tid]; }
  __syncthreads();
  int t = blockIdx.x * 256 + tid;
  float lv[16];
  const float4* lp = (const float4*)(logits + (size_t)t * 16);
  #pragma unroll
  for (int j = 0; j < 4; j++) {
    float4 v = lp[j];
    lv[4*j]   = v.x + gbl[4*j];
    lv[4*j+1] = v.y + gbl[4*j+1];
    lv[4*j+2] = v.z + gbl[4*j+2];
    lv[4*j+3] = v.w + gbl[4*j+3];
  }
  float v0 = -3.402823466e38f, v1 = -3.402823466e38f;
  int i0 = 0, i1 = 0;
  #pragma unroll
  for (int e = 0; e < 16; e++) {
    float v = lv[e];
    if (v > v0) { v1 = v0; i1 = i0; v0 = v; i0 = e; }
    else if (v > v1) { v1 = v; i1 = e; }
  }
  float ew = expf(v1 - v0);
  float inv = 1.f / (1.f + ew);
  e01[t] = make_int2(i0, i1);
  g01[t] = make_float2(inv, ew * inv);
  int r0 = atomicAdd(&hist[i0], 1);
  int r1 = atomicAdd(&hist[i1], 1);
  lrank[2 * t]     = r0;
  lrank[2 * t + 1] = r1;
  __syncthreads();
  if (tid < NEXP) blockhist[blockIdx.x * NEXP + tid] = hist[tid];
}

// ------- scan: expert offsets, per-(block,expert) base, and the flat TILE LIST -------
__global__ void scan2_kernel(const int* __restrict__ blockhist, int* __restrict__ offsets,
                             int* __restrict__ base, int* __restrict__ tile_e,
                             int* __restrict__ tile_mt, int* __restrict__ ntiles) {
  __shared__ int tot[NEXP];
  __shared__ int soff[NEXP + 1];
  __shared__ int tbase[NEXP];
  int e = threadIdx.x;
  if (e < NEXP) {
    int s = 0;
    for (int b = 0; b < NBLK; b++) s += blockhist[b * NEXP + e];
    tot[e] = s;
  }
  __syncthreads();
  if (e == 0) {
    int s = 0, tb = 0;
    for (int i = 0; i < NEXP; i++) {
      soff[i] = s; s += tot[i];
      tbase[i] = tb; tb += (tot[i] + 63) >> 6;
    }
    soff[NEXP] = s;
    *ntiles = tb;
  }
  __syncthreads();
  if (e < NEXP + 1) offsets[e] = soff[e];
  if (e < NEXP) {
    int s = soff[e];
    for (int b = 0; b < NBLK; b++) { base[b * NEXP + e] = s; s += blockhist[b * NEXP + e]; }
    int nt = (tot[e] + 63) >> 6, tb = tbase[e];
    for (int m = 0; m < nt; m++) { tile_e[tb + m] = e; tile_mt[tb + m] = m; }
  }
}

// ---------------- fill: atomic-free scatter using (base, lrank) ----------------
__global__ __launch_bounds__(256) void fill2_kernel(const int2* __restrict__ e01,
                                                    const int* __restrict__ lrank,
                                                    const int* __restrict__ base,
                                                    int* __restrict__ tok_sorted,
                                                    int* __restrict__ route_pos) {
  int b = blockIdx.x;
  int t = b * 256 + threadIdx.x;
  int2 e = e01[t];
  int p0 = base[b * NEXP + e.x] + lrank[2 * t];
  int p1 = base[b * NEXP + e.y] + lrank[2 * t + 1];
  tok_sorted[p0] = t; route_pos[2 * t]     = p0;
  tok_sorted[p1] = t; route_pos[2 * t + 1] = p1;
}

// ------- grouped GEMM: TM=64, TN=128, BK=32, dbuf async LDS, tile-list grid ----
// MODE: 0 = bf16 store, 1 = f32 store, 3 = gate logits epilogue (relu'd tile -> LDS,
//   partial dot vs gate_out_w slice, atomicAdd into L2-resident logits).
// LDA: row stride of A (separate from K extent, so GEMM1 reads the hi block of xs).
template<int MODE, bool RELU>
__global__ __launch_bounds__(256) void moe_gemm_kernel(const __bf16* __restrict__ A,
                                                       const __bf16* __restrict__ Bt,
                                                       const float* __restrict__ bias,
                                                       void* __restrict__ out,
                                                       const int* __restrict__ seg_off,
                                                       const int* __restrict__ gather,
                                                       const int* __restrict__ tile_e,
                                                       const int* __restrict__ tile_mt,
                                                       const int* __restrict__ ntiles,
                                                       const float* __restrict__ gow,
                                                       int LDA, int K, int N) {
  int bx = blockIdx.x;
  if (bx >= *ntiles) return;
  int e  = tile_e[bx];
  int mt = tile_mt[bx];
  int off = seg_off[e];
  int Te  = seg_off[e + 1] - off;
  int nt = blockIdx.y;

  constexpr int SMEM = (MODE == 3) ? (8192 + 64 * 132 * 4) : 24576;
  __shared__ __align__(16) char smem[SMEM];
  __bf16* AlB = (__bf16*)smem;           // [2][64][32]
  __bf16* BlB = (__bf16*)(smem + 8192);  // [2][128][32]

  int tid = threadIdx.x;
  int lane = tid & 63, w = tid >> 6;
  int l16 = lane & 15, quad = lane >> 4;

  int r0 = tid >> 2;
  int q8 = ((tid & 3) ^ ((r0 >> 1) & 3)) * 8;  // slot swizzle (both sides)
  int rowA = mt * 64 + r0;
  int rA = rowA < Te ? rowA : Te - 1;
  size_t ga = gather ? (size_t)gather[off + rA] : (size_t)(off + rA);
  const __bf16* apg  = A + ga * LDA + q8;
  const __bf16* Bte  = Bt + (size_t)e * N * K;
  const __bf16* bpg0 = Bte + (size_t)(nt * 128 + r0) * K + q8;
  const __bf16* bpg1 = bpg0 + (size_t)64 * K;

  __bf16* al0 = AlB;
  __bf16* al1 = AlB + 2048;
  __bf16* bl0 = BlB;
  __bf16* bl1 = BlB + 4096;

  f32x4 acc[4][2];
  #pragma unroll
  for (int i = 0; i < 4; i++)
    #pragma unroll
    for (int j = 0; j < 2; j++) acc[i][j] = {0.f, 0.f, 0.f, 0.f};

  async_cp16(apg, al0 + tid * 8);
  async_cp16(bpg0, bl0 + tid * 8);
  async_cp16(bpg1, bl0 + (tid + 256) * 8);

  int qs = (quad ^ ((l16 >> 1) & 3)) * 8;

  int nIter = K >> 5;
  for (int it = 0; it < nIter; ++it) {
    int buf = it & 1;
    if (it + 1 < nIter) {
      int kb = (it + 1) << 5;
      __bf16* an = buf ? al0 : al1;
      __bf16* bn = buf ? bl0 : bl1;
      async_cp16(apg + kb, an + tid * 8);
      async_cp16(bpg0 + kb, bn + tid * 8);
      async_cp16(bpg1 + kb, bn + (tid + 256) * 8);
      asm volatile("s_waitcnt vmcnt(3)" ::: "memory");
    } else {
      asm volatile("s_waitcnt vmcnt(0)" ::: "memory");
    }
    __builtin_amdgcn_s_barrier();
    asm volatile("" ::: "memory");
    const __bf16* ab = buf ? al1 : al0;
    const __bf16* bb = buf ? bl1 : bl0;
    bf16x8 af[4], bfr[2];
    #pragma unroll
    for (int i = 0; i < 4; i++)
      af[i] = *(const bf16x8*)(ab + (size_t)(i * 16 + l16) * 32 + qs);
    #pragma unroll
    for (int i = 0; i < 2; i++)
      bfr[i] = *(const bf16x8*)(bb + (size_t)(w * 32 + i * 16 + l16) * 32 + qs);
    #pragma unroll
    for (int mi = 0; mi < 4; mi++)
      #pragma unroll
      for (int ni = 0; ni < 2; ni++)
        acc[mi][ni] = __builtin_amdgcn_mfma_f32_16x16x32_bf16(af[mi], bfr[ni], acc[mi][ni], 0, 0, 0);
    asm volatile("" ::: "memory");
    __builtin_amdgcn_s_barrier();
  }

  const float* be = bias + (size_t)e * N;
  if (MODE == 3) {
    // ---- fused logits epilogue ----
    __syncthreads();
    float* wl = (float*)smem;              // [128][16]  gate_out_w slice
    float* ht = (float*)(smem + 8192);     // [64][132]  relu'd hidden tile (fp32)
    if (tid < 128) {
      const float* gr = gow + (size_t)(nt * 128 + tid) * 16;
      #pragma unroll
      for (int j = 0; j < 4; j++)
        *(float4*)&wl[tid * 16 + j * 4] = *(const float4*)&gr[j * 4];
    }
    float bv[2];
    #pragma unroll
    for (int ni = 0; ni < 2; ni++) bv[ni] = be[nt * 128 + w * 32 + ni * 16 + l16];
    #pragma unroll
    for (int mi = 0; mi < 4; mi++)
      #pragma unroll
      for (int ni = 0; ni < 2; ni++)
        #pragma unroll
        for (int r = 0; r < 4; r++) {
          int row = mi * 16 + quad * 4 + r;
          int col = w * 32 + ni * 16 + l16;
          ht[row * 132 + col] = fmaxf(acc[mi][ni][r] + bv[ni], 0.f);
        }
    __syncthreads();
    int t = tid >> 2, e4 = (tid & 3) * 4;
    float s0 = 0.f, s1 = 0.f, s2 = 0.f, s3 = 0.f;
    #pragma unroll 4
    for (int h = 0; h < 128; h++) {
      float hv = ht[t * 132 + h];
      const float* wr = &wl[h * 16 + e4];
      s0 = fmaf(hv, wr[0], s0);
      s1 = fmaf(hv, wr[1], s1);
      s2 = fmaf(hv, wr[2], s2);
      s3 = fmaf(hv, wr[3], s3);
    }
    float* lp = (float*)out + (size_t)(mt * 64 + t) * 16 + e4;
    atomicAdd(lp + 0, s0);
    atomicAdd(lp + 1, s1);
    atomicAdd(lp + 2, s2);
    atomicAdd(lp + 3, s3);
    return;
  }

  #pragma unroll
  for (int ni = 0; ni < 2; ni++) {
    int col = nt * 128 + w * 32 + ni * 16 + l16;
    float bv = be[col];
    #pragma unroll
    for (int mi = 0; mi < 4; mi++) {
      #pragma unroll
      for (int r = 0; r < 4; r++) {
        int row_in = mt * 64 + mi * 16 + quad * 4 + r;
        if (row_in < Te) {
          float v = acc[mi][ni][r] + bv;
          if (RELU) v = fmaxf(v, 0.f);
          size_t orow = (size_t)(off + row_in);
          if (MODE == 1) ((float*)out)[orow * N + col] = v;
          else ((__bf16*)out)[orow * N + col] = (__bf16)v;
        }
      }
    }
  }
}

// ---------------- final combine: out[t] = g0*Y[p0] + g1*Y[p1]  (Y in bf16) ----------------
__global__ void combine_kernel(const __bf16* __restrict__ Y, const int* __restrict__ route_pos,
                               const float2* __restrict__ g01, float* __restrict__ out) {
  int gid = blockIdx.x * blockDim.x + threadIdx.x;
  int t = gid >> 6, c = (gid & 63) << 2;
  if (t >= NTOK) return;
  int p0 = route_pos[2 * t], p1 = route_pos[2 * t + 1];
  float2 g = g01[t];
  bf16x4 y0 = *(const bf16x4*)&Y[(size_t)p0 * DOUT + c];
  bf16x4 y1 = *(const bf16x4*)&Y[(size_t)p1 * DOUT + c];
  float4 o;
  o.x = g.x * (float)y0[0] + g.y * (float)y1[0];
  o.y = g.x * (float)y0[1] + g.y * (float)y1[1];
  o.z = g.x * (float)y0[2] + g.y * (float)y1[2];
  o.w = g.x * (float)y0[3] + g.y * (float)y1[3];
  *(float4*)&out[(size_t)t * DOUT + c] = o;
}

// ---------------- launcher ----------------
extern "C" void kernel_launch(void* const* d_in, const int* in_sizes, int n_in,
                              void* d_out, int out_size, void* d_ws, size_t ws_size,
                              hipStream_t stream) {
  const float* x          = (const float*)d_in[0];
  const float* gate_w     = (const float*)d_in[1];
  const float* gate_b     = (const float*)d_in[2];
  const float* gate_out_w = (const float*)d_in[3];
  const float* gate_out_b = (const float*)d_in[4];
  const float* w1         = (const float*)d_in[5];
  const float* b1         = (const float*)d_in[6];
  const float* w2         = (const float*)d_in[7];
  const float* b2         = (const float*)d_in[8];
  const float* w3         = (const float*)d_in[9];
  const float* b3         = (const float*)d_in[10];
  float* out = (float*)d_out;

  char* ws = (char*)d_ws;
  size_t o = 0;
  auto alloc = [&](size_t bytes) -> void* {
    o = (o + 255) & ~(size_t)255;
    void* p = ws + o;
    o += bytes;
    return p;
  };

  __bf16* w1t  = (__bf16*)alloc((size_t)NEXP * HID * DIN * 2);
  __bf16* w2t  = (__bf16*)alloc((size_t)NEXP * HID * HID * 2);
  __bf16* w3t  = (__bf16*)alloc((size_t)NEXP * DOUT * HID * 2);
  __bf16* gwt  = (__bf16*)alloc((size_t)HID * GK * 2);
  __bf16* H1   = (__bf16*)alloc((size_t)(NKA + 128) * HID * 2);
  // xs (gate split input + GEMM1 hi input; dead after GEMM1) aliases H2
  size_t r3 = (size_t)NTOK * GK * 2;
  size_t r4 = (size_t)(NKA + 128) * HID * 2;
  void* region2 = alloc(r3 > r4 ? r3 : r4);
  __bf16* xs = (__bf16*)region2;
  __bf16* H2 = (__bf16*)region2;
  float* logits    = (float*)alloc((size_t)NTOK * 16 * 4);
  int2*  e01       = (int2*)alloc((size_t)NTOK * 8);
  float2* g01      = (float2*)alloc((size_t)NTOK * 8);
  int*   offsets   = (int*)alloc((NEXP + 1) * 4);
  int*   blockhist = (int*)alloc((size_t)NBLK * NEXP * 4);
  int*   base      = (int*)alloc((size_t)NBLK * NEXP * 4);
  int*   lrank     = (int*)alloc((size_t)NTOK * 2 * 4);
  int*   tok_sorted= (int*)alloc((size_t)(NKA + 128) * 4);
  int*   route_pos = (int*)alloc((size_t)NTOK * 2 * 4);
  int*   tile_e    = (int*)alloc(MAXTILE * 4);
  int*   tile_mt   = (int*)alloc(MAXTILE * 4);
  int*   ntiles    = (int*)alloc(4);
  int*   gtile_e   = (int*)alloc(128 * 4);
  int*   gtile_mt  = (int*)alloc(128 * 4);
  int*   gntiles   = (int*)alloc(4);
  int*   gseg      = (int*)alloc(2 * 4);
  __bf16* Y        = (__bf16*)alloc((size_t)(NKA + 128) * DOUT * 2);
  (void)ws_size; (void)n_in; (void)in_sizes; (void)out_size;

  // 1. fused prep (x split + gate weight split + 3 weight transposes + zero(logits))
  prep_kernel<<<10496, 256, 0, stream>>>(x, xs, gate_w, gwt,
                                         w1, w1t, w2, w2t, w3, w3t,
                                         gtile_e, gtile_mt, gntiles, gseg, logits);

  // 2. gate GEMM (bf16x2-split K=768) with fused logits epilogue -> logits
  moe_gemm_kernel<3, true><<<dim3(NTOK / 64, HID / 128), 256, 0, stream>>>(
      xs, gwt, gate_b, logits, gseg, nullptr, gtile_e, gtile_mt, gntiles,
      gate_out_w, GK, GK, HID);

  // 3-5. top-2 routing + scan + fill
  top2_kernel<<<NBLK, 256, 0, stream>>>(logits, gate_out_b, e01, g01, lrank, blockhist);
  scan2_kernel<<<1, 64, 0, stream>>>(blockhist, offsets, base, tile_e, tile_mt, ntiles);
  fill2_kernel<<<NBLK, 256, 0, stream>>>(e01, lrank, base, tok_sorted, route_pos);

  // 6-8. expert GEMMs (GEMM1 reads the hi block of xs via LDA=GK)
  moe_gemm_kernel<0, true><<<dim3(MAXTILE, HID / 128), 256, 0, stream>>>(
      xs, w1t, b1, H1, offsets, tok_sorted, tile_e, tile_mt, ntiles,
      nullptr, GK, DIN, HID);
  moe_gemm_kernel<0, true><<<dim3(MAXTILE, HID / 128), 256, 0, stream>>>(
      H1, w2t, b2, H2, offsets, nullptr, tile_e, tile_mt, ntiles,
      nullptr, HID, HID, HID);
  moe_gemm_kernel<0, false><<<dim3(MAXTILE, DOUT / 128), 256, 0, stream>>>(
      H2, w3t, b3, Y, offsets, nullptr, tile_e, tile_mt, ntiles,
      nullptr, HID, HID, DOUT);

  // 9. combine (bf16 Y)
  combine_kernel<<<(NTOK * 64) / 256, 256, 0, stream>>>(Y, route_pos, g01, out);
}

// Round 10
// 201.190 us; speedup vs baseline: 1.0132x; 1.0132x over previous
//
#include <hip/hip_runtime.h>
#include <hip/hip_bf16.h>
#include <stdint.h>

#define NTOK 8192
#define DIN  256
#define DOUT 256
#define NEXP 16
#define HID  512
#define NKA  (NTOK*2)    // total assignments
#define NBLK (NTOK/256)  // routing/fill blocks (256 tokens each)
#define MAXTILE 272      // sum ceil(Te/64) <= 16384/64 + 16
#define GK 768           // gate split-GEMM K: [x_hi | x_lo | x_hi]

typedef __bf16 bf16x8 __attribute__((ext_vector_type(8)));
typedef __bf16 bf16x4 __attribute__((ext_vector_type(4)));
typedef float  f32x4  __attribute__((ext_vector_type(4)));

// async 16B global -> LDS (DMA; wave-uniform LDS base + lane*16)
__device__ __forceinline__ void async_cp16(const __bf16* g, __bf16* l) {
  __builtin_amdgcn_global_load_lds(
      (const __attribute__((address_space(1))) unsigned int*)g,
      (__attribute__((address_space(3))) unsigned int*)l, 16, 0, 0);
}

// ------------- shared transpose body: src[k][e][n] fp32 -> dst[e][n][k] bf16 -------------
__device__ __forceinline__ void transpose_cvt_body(const float* __restrict__ src,
                                                   __bf16* __restrict__ dst,
                                                   int K, int N, int bx, int by, int bz,
                                                   int tx, int ty, float (*t)[33]) {
  int e = bz, k0 = bx * 32, n0 = by * 32;
  #pragma unroll
  for (int j = 0; j < 4; j++) {
    int kl = ty + j * 8;
    t[kl][tx] = src[(size_t)(k0 + kl) * (NEXP * N) + (size_t)e * N + n0 + tx];
  }
  __syncthreads();
  #pragma unroll
  for (int j = 0; j < 4; j++) {
    int nl = ty + j * 8;
    dst[(size_t)e * N * K + (size_t)(n0 + nl) * K + k0 + tx] = (__bf16)t[tx][nl];
  }
}

// ---------------- prep: x bf16x2 split + gate weight split + zero(logits) ----------------
__global__ __launch_bounds__(256) void prep_kernel(
    const float* __restrict__ x, __bf16* __restrict__ xs,
    const float* __restrict__ gw, __bf16* __restrict__ gwt,
    float* __restrict__ logitz) {
  __shared__ float t[32][33];
  int idx = blockIdx.x;
  int tid = threadIdx.x;
  int tx = tid & 31, ty = tid >> 5;
  if (idx < 2048) {
    // cvt_x: fp32 -> bf16x2 split rows [hi | lo | hi]  (hi block doubles as GEMM1 input)
    int i = idx * 256 + tid;
    float4 v = ((const float4*)x)[i];
    int base = i * 4;
    int tk = base >> 8, c = base & 255;
    bf16x4 hi = { (__bf16)v.x, (__bf16)v.y, (__bf16)v.z, (__bf16)v.w };
    bf16x4 lo = { (__bf16)(v.x - (float)hi[0]), (__bf16)(v.y - (float)hi[1]),
                  (__bf16)(v.z - (float)hi[2]), (__bf16)(v.w - (float)hi[3]) };
    __bf16* row = xs + (size_t)tk * GK + c;
    *(bf16x4*)(row)       = hi;
    *(bf16x4*)(row + 256) = lo;
    *(bf16x4*)(row + 512) = hi;
  } else if (idx < 2176) {
    // gate weight: transpose + bf16x2 split into B^T layout [n][GK]
    int g = idx - 2048;
    int k0 = (g & 7) * 32, n0 = (g >> 3) * 32;
    #pragma unroll
    for (int j = 0; j < 4; j++) {
      int kl = ty + j * 8;
      t[kl][tx] = gw[(size_t)(k0 + kl) * HID + n0 + tx];
    }
    __syncthreads();
    #pragma unroll
    for (int j = 0; j < 4; j++) {
      int nl = ty + j * 8;
      float v = t[tx][nl];
      __bf16 hi = (__bf16)v;
      __bf16 lo = (__bf16)(v - (float)hi);
      __bf16* drow = gwt + (size_t)(n0 + nl) * GK + k0 + tx;
      drow[0]   = hi;
      drow[256] = hi;
      drow[512] = lo;
    }
  } else {
    // zero the logits accumulator (gate GEMM combines partials via atomicAdd)
    int i = (idx - 2176) * 256 + tid;
    ((float4*)logitz)[i] = make_float4(0.f, 0.f, 0.f, 0.f);
  }
}

// ---- gate GEMM (blocks 0..511) + expert weight transposes (blocks 512..8703) ----
// Gate: TM=64, TN=128, BK=32, K=768 bf16x2-split, fused logits epilogue (atomicAdd
// into L2-resident logits). Transposes ride along and fill idle CU slots.
__global__ __launch_bounds__(256) void gate_fused_kernel(
    const __bf16* __restrict__ xs, const __bf16* __restrict__ gwt,
    const float* __restrict__ gate_b, float* __restrict__ logits,
    const float* __restrict__ gow,
    const float* __restrict__ w1, __bf16* __restrict__ w1t,
    const float* __restrict__ w2, __bf16* __restrict__ w2t,
    const float* __restrict__ w3, __bf16* __restrict__ w3t) {
  __shared__ __align__(16) char smem[8192 + 64 * 132 * 4];
  int bx = blockIdx.x;
  int tid = threadIdx.x;

  if (bx >= 512) {
    // ---- transpose-convert roles ----
    float (*t)[33] = (float (*)[33])smem;
    int tx = tid & 31, ty = tid >> 5;
    int g = bx - 512;
    if (g < 2048) {        // w1: K=256 (8), N=512 (16), E=16
      transpose_cvt_body(w1, w1t, DIN, HID, g & 7, (g >> 3) & 15, g >> 7, tx, ty, t);
    } else if (g < 6144) { // w2: K=512 (16), N=512 (16), E=16
      int g2 = g - 2048;
      transpose_cvt_body(w2, w2t, HID, HID, g2 & 15, (g2 >> 4) & 15, g2 >> 8, tx, ty, t);
    } else {               // w3: K=512 (16), N=256 (8), E=16
      int g3 = g - 6144;
      transpose_cvt_body(w3, w3t, HID, DOUT, g3 & 15, (g3 >> 4) & 7, g3 >> 7, tx, ty, t);
    }
    return;
  }

  // ---- gate GEMM role ----
  int mt = bx >> 2, nt = bx & 3;
  __bf16* AlB = (__bf16*)smem;           // [2][64][32]
  __bf16* BlB = (__bf16*)(smem + 8192);  // [2][128][32]

  int lane = tid & 63, w = tid >> 6;
  int l16 = lane & 15, quad = lane >> 4;

  int r0 = tid >> 2;
  int q8 = ((tid & 3) ^ ((r0 >> 1) & 3)) * 8;  // slot swizzle (both sides)
  const __bf16* apg  = xs + (size_t)(mt * 64 + r0) * GK + q8;
  const __bf16* bpg0 = gwt + (size_t)(nt * 128 + r0) * GK + q8;
  const __bf16* bpg1 = bpg0 + (size_t)64 * GK;

  __bf16* al0 = AlB;
  __bf16* al1 = AlB + 2048;
  __bf16* bl0 = BlB;
  __bf16* bl1 = BlB + 4096;

  f32x4 acc[4][2];
  #pragma unroll
  for (int i = 0; i < 4; i++)
    #pragma unroll
    for (int j = 0; j < 2; j++) acc[i][j] = {0.f, 0.f, 0.f, 0.f};

  async_cp16(apg, al0 + tid * 8);
  async_cp16(bpg0, bl0 + tid * 8);
  async_cp16(bpg1, bl0 + (tid + 256) * 8);

  int qs = (quad ^ ((l16 >> 1) & 3)) * 8;

  const int nIter = GK >> 5;  // 24
  for (int it = 0; it < nIter; ++it) {
    int buf = it & 1;
    if (it + 1 < nIter) {
      int kb = (it + 1) << 5;
      __bf16* an = buf ? al0 : al1;
      __bf16* bn = buf ? bl0 : bl1;
      async_cp16(apg + kb, an + tid * 8);
      async_cp16(bpg0 + kb, bn + tid * 8);
      async_cp16(bpg1 + kb, bn + (tid + 256) * 8);
      asm volatile("s_waitcnt vmcnt(3)" ::: "memory");
    } else {
      asm volatile("s_waitcnt vmcnt(0)" ::: "memory");
    }
    __builtin_amdgcn_s_barrier();
    asm volatile("" ::: "memory");
    const __bf16* ab = buf ? al1 : al0;
    const __bf16* bb = buf ? bl1 : bl0;
    bf16x8 af[4], bfr[2];
    #pragma unroll
    for (int i = 0; i < 4; i++)
      af[i] = *(const bf16x8*)(ab + (size_t)(i * 16 + l16) * 32 + qs);
    #pragma unroll
    for (int i = 0; i < 2; i++)
      bfr[i] = *(const bf16x8*)(bb + (size_t)(w * 32 + i * 16 + l16) * 32 + qs);
    #pragma unroll
    for (int mi = 0; mi < 4; mi++)
      #pragma unroll
      for (int ni = 0; ni < 2; ni++)
        acc[mi][ni] = __builtin_amdgcn_mfma_f32_16x16x32_bf16(af[mi], bfr[ni], acc[mi][ni], 0, 0, 0);
    asm volatile("" ::: "memory");
    __builtin_amdgcn_s_barrier();
  }

  // ---- fused logits epilogue ----
  __syncthreads();
  float* wl = (float*)smem;              // [128][16]  gate_out_w slice
  float* ht = (float*)(smem + 8192);     // [64][132]  relu'd hidden tile (fp32)
  if (tid < 128) {
    const float* gr = gow + (size_t)(nt * 128 + tid) * 16;
    #pragma unroll
    for (int j = 0; j < 4; j++)
      *(float4*)&wl[tid * 16 + j * 4] = *(const float4*)&gr[j * 4];
  }
  float bv[2];
  #pragma unroll
  for (int ni = 0; ni < 2; ni++) bv[ni] = gate_b[nt * 128 + w * 32 + ni * 16 + l16];
  #pragma unroll
  for (int mi = 0; mi < 4; mi++)
    #pragma unroll
    for (int ni = 0; ni < 2; ni++)
      #pragma unroll
      for (int r = 0; r < 4; r++) {
        int row = mi * 16 + quad * 4 + r;
        int col = w * 32 + ni * 16 + l16;
        ht[row * 132 + col] = fmaxf(acc[mi][ni][r] + bv[ni], 0.f);
      }
  __syncthreads();
  int t = tid >> 2, e4 = (tid & 3) * 4;
  float s0 = 0.f, s1 = 0.f, s2 = 0.f, s3 = 0.f;
  #pragma unroll 4
  for (int h = 0; h < 128; h++) {
    float hv = ht[t * 132 + h];
    const float* wr = &wl[h * 16 + e4];
    s0 = fmaf(hv, wr[0], s0);
    s1 = fmaf(hv, wr[1], s1);
    s2 = fmaf(hv, wr[2], s2);
    s3 = fmaf(hv, wr[3], s3);
  }
  float* lp = logits + (size_t)(mt * 64 + t) * 16 + e4;
  atomicAdd(lp + 0, s0);
  atomicAdd(lp + 1, s1);
  atomicAdd(lp + 2, s2);
  atomicAdd(lp + 3, s3);
}

// ---------------- top-2 + softmax + block-local histogram/ranks ----------------
__global__ __launch_bounds__(256) void top2_kernel(const float* __restrict__ logits,
                                                   const float* __restrict__ gb,
                                                   int2* __restrict__ e01,
                                                   float2* __restrict__ g01,
                                                   int* __restrict__ lrank,
                                                   int* __restrict__ blockhist) {
  __shared__ int hist[NEXP];
  __shared__ float gbl[NEXP];
  int tid = threadIdx.x;
  if (tid < NEXP) { hist[tid] = 0; gbl[tid] = gb[tid]; }
  __syncthreads();
  int t = blockIdx.x * 256 + tid;
  float lv[16];
  const float4* lp = (const float4*)(logits + (size_t)t * 16);
  #pragma unroll
  for (int j = 0; j < 4; j++) {
    float4 v = lp[j];
    lv[4*j]   = v.x + gbl[4*j];
    lv[4*j+1] = v.y + gbl[4*j+1];
    lv[4*j+2] = v.z + gbl[4*j+2];
    lv[4*j+3] = v.w + gbl[4*j+3];
  }
  float v0 = -3.402823466e38f, v1 = -3.402823466e38f;
  int i0 = 0, i1 = 0;
  #pragma unroll
  for (int e = 0; e < 16; e++) {
    float v = lv[e];
    if (v > v0) { v1 = v0; i1 = i0; v0 = v; i0 = e; }
    else if (v > v1) { v1 = v; i1 = e; }
  }
  float ew = expf(v1 - v0);
  float inv = 1.f / (1.f + ew);
  e01[t] = make_int2(i0, i1);
  g01[t] = make_float2(inv, ew * inv);
  int r0 = atomicAdd(&hist[i0], 1);
  int r1 = atomicAdd(&hist[i1], 1);
  lrank[2 * t]     = r0;
  lrank[2 * t + 1] = r1;
  __syncthreads();
  if (tid < NEXP) blockhist[blockIdx.x * NEXP + tid] = hist[tid];
}

// ------ fill + redundant scan: each block recomputes the small scan in LDS; block 0
// additionally writes offsets + flat tile list. Replaces the serial scan2 kernel. ------
__global__ __launch_bounds__(256) void fillscan_kernel(const int2* __restrict__ e01,
                                                       const int* __restrict__ lrank,
                                                       const int* __restrict__ blockhist,
                                                       int* __restrict__ tok_sorted,
                                                       int* __restrict__ route_pos,
                                                       int* __restrict__ offsets,
                                                       int* __restrict__ tile_e,
                                                       int* __restrict__ tile_mt,
                                                       int* __restrict__ ntiles) {
  __shared__ int tot_s[NEXP], pre_s[NEXP], soff[NEXP + 1], base_l[NEXP], tbase[NEXP];
  int b = blockIdx.x;
  int tid = threadIdx.x;
  if (tid < NEXP) {
    int s_all = 0, s_pre = 0;
    for (int bb = 0; bb < NBLK; bb++) {
      int h = blockhist[bb * NEXP + tid];
      s_pre += (bb < b) ? h : 0;
      s_all += h;
    }
    tot_s[tid] = s_all;
    pre_s[tid] = s_pre;
  }
  __syncthreads();
  if (tid == 0) {
    int s = 0, tb = 0;
    for (int i = 0; i < NEXP; i++) {
      soff[i] = s; s += tot_s[i];
      tbase[i] = tb; tb += (tot_s[i] + 63) >> 6;
    }
    soff[NEXP] = s;
    if (b == 0) *ntiles = tb;
  }
  __syncthreads();
  if (tid < NEXP) base_l[tid] = soff[tid] + pre_s[tid];
  if (b == 0) {
    if (tid < NEXP + 1) offsets[tid] = soff[tid];
    if (tid < NEXP) {
      int nt = (tot_s[tid] + 63) >> 6, tb0 = tbase[tid];
      for (int m = 0; m < nt; m++) { tile_e[tb0 + m] = tid; tile_mt[tb0 + m] = m; }
    }
  }
  __syncthreads();
  int t = b * 256 + tid;
  int2 e = e01[t];
  int p0 = base_l[e.x] + lrank[2 * t];
  int p1 = base_l[e.y] + lrank[2 * t + 1];
  tok_sorted[p0] = t; route_pos[2 * t]     = p0;
  tok_sorted[p1] = t; route_pos[2 * t + 1] = p1;
}

// ------- grouped expert GEMM: TM=64, TN=128, BK=32, dbuf async LDS, tile-list grid ----
// bf16 store; LDA separate from K so GEMM1 reads the hi block of xs (LDA=GK).
template<bool RELU>
__global__ __launch_bounds__(256) void moe_gemm_kernel(const __bf16* __restrict__ A,
                                                       const __bf16* __restrict__ Bt,
                                                       const float* __restrict__ bias,
                                                       __bf16* __restrict__ out,
                                                       const int* __restrict__ seg_off,
                                                       const int* __restrict__ gather,
                                                       const int* __restrict__ tile_e,
                                                       const int* __restrict__ tile_mt,
                                                       const int* __restrict__ ntiles,
                                                       int LDA, int K, int N) {
  int bx = blockIdx.x;
  if (bx >= *ntiles) return;
  int e  = tile_e[bx];
  int mt = tile_mt[bx];
  int off = seg_off[e];
  int Te  = seg_off[e + 1] - off;
  int nt = blockIdx.y;

  __shared__ __align__(16) char smem[24576];
  __bf16* AlB = (__bf16*)smem;           // [2][64][32]
  __bf16* BlB = (__bf16*)(smem + 8192);  // [2][128][32]

  int tid = threadIdx.x;
  int lane = tid & 63, w = tid >> 6;
  int l16 = lane & 15, quad = lane >> 4;

  int r0 = tid >> 2;
  int q8 = ((tid & 3) ^ ((r0 >> 1) & 3)) * 8;  // slot swizzle (both sides)
  int rowA = mt * 64 + r0;
  int rA = rowA < Te ? rowA : Te - 1;
  size_t ga = gather ? (size_t)gather[off + rA] : (size_t)(off + rA);
  const __bf16* apg  = A + ga * LDA + q8;
  const __bf16* Bte  = Bt + (size_t)e * N * K;
  const __bf16* bpg0 = Bte + (size_t)(nt * 128 + r0) * K + q8;
  const __bf16* bpg1 = bpg0 + (size_t)64 * K;

  __bf16* al0 = AlB;
  __bf16* al1 = AlB + 2048;
  __bf16* bl0 = BlB;
  __bf16* bl1 = BlB + 4096;

  f32x4 acc[4][2];
  #pragma unroll
  for (int i = 0; i < 4; i++)
    #pragma unroll
    for (int j = 0; j < 2; j++) acc[i][j] = {0.f, 0.f, 0.f, 0.f};

  async_cp16(apg, al0 + tid * 8);
  async_cp16(bpg0, bl0 + tid * 8);
  async_cp16(bpg1, bl0 + (tid + 256) * 8);

  int qs = (quad ^ ((l16 >> 1) & 3)) * 8;

  int nIter = K >> 5;
  for (int it = 0; it < nIter; ++it) {
    int buf = it & 1;
    if (it + 1 < nIter) {
      int kb = (it + 1) << 5;
      __bf16* an = buf ? al0 : al1;
      __bf16* bn = buf ? bl0 : bl1;
      async_cp16(apg + kb, an + tid * 8);
      async_cp16(bpg0 + kb, bn + tid * 8);
      async_cp16(bpg1 + kb, bn + (tid + 256) * 8);
      asm volatile("s_waitcnt vmcnt(3)" ::: "memory");
    } else {
      asm volatile("s_waitcnt vmcnt(0)" ::: "memory");
    }
    __builtin_amdgcn_s_barrier();
    asm volatile("" ::: "memory");
    const __bf16* ab = buf ? al1 : al0;
    const __bf16* bb = buf ? bl1 : bl0;
    bf16x8 af[4], bfr[2];
    #pragma unroll
    for (int i = 0; i < 4; i++)
      af[i] = *(const bf16x8*)(ab + (size_t)(i * 16 + l16) * 32 + qs);
    #pragma unroll
    for (int i = 0; i < 2; i++)
      bfr[i] = *(const bf16x8*)(bb + (size_t)(w * 32 + i * 16 + l16) * 32 + qs);
    #pragma unroll
    for (int mi = 0; mi < 4; mi++)
      #pragma unroll
      for (int ni = 0; ni < 2; ni++)
        acc[mi][ni] = __builtin_amdgcn_mfma_f32_16x16x32_bf16(af[mi], bfr[ni], acc[mi][ni], 0, 0, 0);
    asm volatile("" ::: "memory");
    __builtin_amdgcn_s_barrier();
  }

  const float* be = bias + (size_t)e * N;
  #pragma unroll
  for (int ni = 0; ni < 2; ni++) {
    int col = nt * 128 + w * 32 + ni * 16 + l16;
    float bv = be[col];
    #pragma unroll
    for (int mi = 0; mi < 4; mi++) {
      #pragma unroll
      for (int r = 0; r < 4; r++) {
        int row_in = mt * 64 + mi * 16 + quad * 4 + r;
        if (row_in < Te) {
          float v = acc[mi][ni][r] + bv;
          if (RELU) v = fmaxf(v, 0.f);
          out[(size_t)(off + row_in) * N + col] = (__bf16)v;
        }
      }
    }
  }
}

// ---------------- final combine: out[t] = g0*Y[p0] + g1*Y[p1]  (Y in bf16) ----------------
__global__ void combine_kernel(const __bf16* __restrict__ Y, const int* __restrict__ route_pos,
                               const float2* __restrict__ g01, float* __restrict__ out) {
  int gid = blockIdx.x * blockDim.x + threadIdx.x;
  int t = gid >> 6, c = (gid & 63) << 2;
  if (t >= NTOK) return;
  int p0 = route_pos[2 * t], p1 = route_pos[2 * t + 1];
  float2 g = g01[t];
  bf16x4 y0 = *(const bf16x4*)&Y[(size_t)p0 * DOUT + c];
  bf16x4 y1 = *(const bf16x4*)&Y[(size_t)p1 * DOUT + c];
  float4 o;
  o.x = g.x * (float)y0[0] + g.y * (float)y1[0];
  o.y = g.x * (float)y0[1] + g.y * (float)y1[1];
  o.z = g.x * (float)y0[2] + g.y * (float)y1[2];
  o.w = g.x * (float)y0[3] + g.y * (float)y1[3];
  *(float4*)&out[(size_t)t * DOUT + c] = o;
}

// ---------------- launcher ----------------
extern "C" void kernel_launch(void* const* d_in, const int* in_sizes, int n_in,
                              void* d_out, int out_size, void* d_ws, size_t ws_size,
                              hipStream_t stream) {
  const float* x          = (const float*)d_in[0];
  const float* gate_w     = (const float*)d_in[1];
  const float* gate_b     = (const float*)d_in[2];
  const float* gate_out_w = (const float*)d_in[3];
  const float* gate_out_b = (const float*)d_in[4];
  const float* w1         = (const float*)d_in[5];
  const float* b1         = (const float*)d_in[6];
  const float* w2         = (const float*)d_in[7];
  const float* b2         = (const float*)d_in[8];
  const float* w3         = (const float*)d_in[9];
  const float* b3         = (const float*)d_in[10];
  float* out = (float*)d_out;

  char* ws = (char*)d_ws;
  size_t o = 0;
  auto alloc = [&](size_t bytes) -> void* {
    o = (o + 255) & ~(size_t)255;
    void* p = ws + o;
    o += bytes;
    return p;
  };

  __bf16* w1t  = (__bf16*)alloc((size_t)NEXP * HID * DIN * 2);
  __bf16* w2t  = (__bf16*)alloc((size_t)NEXP * HID * HID * 2);
  __bf16* w3t  = (__bf16*)alloc((size_t)NEXP * DOUT * HID * 2);
  __bf16* gwt  = (__bf16*)alloc((size_t)HID * GK * 2);
  __bf16* H1   = (__bf16*)alloc((size_t)(NKA + 128) * HID * 2);
  // xs (gate split input + GEMM1 hi input; dead after GEMM1) aliases H2
  size_t r3 = (size_t)NTOK * GK * 2;
  size_t r4 = (size_t)(NKA + 128) * HID * 2;
  void* region2 = alloc(r3 > r4 ? r3 : r4);
  __bf16* xs = (__bf16*)region2;
  __bf16* H2 = (__bf16*)region2;
  float* logits    = (float*)alloc((size_t)NTOK * 16 * 4);
  int2*  e01       = (int2*)alloc((size_t)NTOK * 8);
  float2* g01      = (float2*)alloc((size_t)NTOK * 8);
  int*   offsets   = (int*)alloc((NEXP + 1) * 4);
  int*   blockhist = (int*)alloc((size_t)NBLK * NEXP * 4);
  int*   lrank     = (int*)alloc((size_t)NTOK * 2 * 4);
  int*   tok_sorted= (int*)alloc((size_t)(NKA + 128) * 4);
  int*   route_pos = (int*)alloc((size_t)NTOK * 2 * 4);
  int*   tile_e    = (int*)alloc(MAXTILE * 4);
  int*   tile_mt   = (int*)alloc(MAXTILE * 4);
  int*   ntiles    = (int*)alloc(4);
  __bf16* Y        = (__bf16*)alloc((size_t)(NKA + 128) * DOUT * 2);
  (void)ws_size; (void)n_in; (void)in_sizes; (void)out_size;

  // 1. prep (x split + gate weight split + zero(logits))
  prep_kernel<<<2304, 256, 0, stream>>>(x, xs, gate_w, gwt, logits);

  // 2. gate GEMM + fused logits epilogue, with expert-weight transposes riding along
  gate_fused_kernel<<<8704, 256, 0, stream>>>(xs, gwt, gate_b, logits, gate_out_w,
                                              w1, w1t, w2, w2t, w3, w3t);

  // 3-4. top-2 routing, then fill+scan (scan recomputed per block; block 0 writes lists)
  top2_kernel<<<NBLK, 256, 0, stream>>>(logits, gate_out_b, e01, g01, lrank, blockhist);
  fillscan_kernel<<<NBLK, 256, 0, stream>>>(e01, lrank, blockhist, tok_sorted, route_pos,
                                            offsets, tile_e, tile_mt, ntiles);

  // 5-7. expert GEMMs (GEMM1 reads the hi block of xs via LDA=GK)
  moe_gemm_kernel<true><<<dim3(MAXTILE, HID / 128), 256, 0, stream>>>(
      xs, w1t, b1, H1, offsets, tok_sorted, tile_e, tile_mt, ntiles, GK, DIN, HID);
  moe_gemm_kernel<true><<<dim3(MAXTILE, HID / 128), 256, 0, stream>>>(
      H1, w2t, b2, H2, offsets, nullptr, tile_e, tile_mt, ntiles, HID, HID, HID);
  moe_gemm_kernel<false><<<dim3(MAXTILE, DOUT / 128), 256, 0, stream>>>(
      H2, w3t, b3, Y, offsets, nullptr, tile_e, tile_mt, ntiles, HID, HID, DOUT);

  // 8. combine (bf16 Y)
  combine_kernel<<<(NTOK * 64) / 256, 256, 0, stream>>>(Y, route_pos, g01, out);
}

// Round 11
// 193.927 us; speedup vs baseline: 1.0511x; 1.0375x over previous
//
#include <hip/hip_runtime.h>
#include <hip/hip_bf16.h>
#include <stdint.h>

#define NTOK 8192
#define DIN  256
#define DOUT 256
#define NEXP 16
#define HID  512
#define NKA  (NTOK*2)    // total assignments
#define NBLK (NTOK/256)  // routing/fill blocks (256 tokens each)
#define MAXTILE 272      // sum ceil(Te/64) <= 16384/64 + 16  (= 8*34, XCD-swizzle friendly)
#define GK 768           // gate split-GEMM K: [x_hi | x_lo | x_hi]

typedef __bf16 bf16x8 __attribute__((ext_vector_type(8)));
typedef __bf16 bf16x4 __attribute__((ext_vector_type(4)));
typedef float  f32x4  __attribute__((ext_vector_type(4)));

// async 16B global -> LDS (DMA; wave-uniform LDS base + lane*16)
__device__ __forceinline__ void async_cp16(const __bf16* g, __bf16* l) {
  __builtin_amdgcn_global_load_lds(
      (const __attribute__((address_space(1))) unsigned int*)g,
      (__attribute__((address_space(3))) unsigned int*)l, 16, 0, 0);
}

// ------------- shared transpose body: src[k][e][n] fp32 -> dst[e][n][k] bf16 -------------
__device__ __forceinline__ void transpose_cvt_body(const float* __restrict__ src,
                                                   __bf16* __restrict__ dst,
                                                   int K, int N, int bx, int by, int bz,
                                                   int tx, int ty, float (*t)[33]) {
  int e = bz, k0 = bx * 32, n0 = by * 32;
  #pragma unroll
  for (int j = 0; j < 4; j++) {
    int kl = ty + j * 8;
    t[kl][tx] = src[(size_t)(k0 + kl) * (NEXP * N) + (size_t)e * N + n0 + tx];
  }
  __syncthreads();
  #pragma unroll
  for (int j = 0; j < 4; j++) {
    int nl = ty + j * 8;
    dst[(size_t)e * N * K + (size_t)(n0 + nl) * K + k0 + tx] = (__bf16)t[tx][nl];
  }
}

// ---------------- prep: x bf16x2 split + gate weight split + zero(logits) ----------------
__global__ __launch_bounds__(256) void prep_kernel(
    const float* __restrict__ x, __bf16* __restrict__ xs,
    const float* __restrict__ gw, __bf16* __restrict__ gwt,
    float* __restrict__ logitz) {
  __shared__ float t[32][33];
  int idx = blockIdx.x;
  int tid = threadIdx.x;
  int tx = tid & 31, ty = tid >> 5;
  if (idx < 2048) {
    // cvt_x: fp32 -> bf16x2 split rows [hi | lo | hi]  (hi block doubles as GEMM1 input)
    int i = idx * 256 + tid;
    float4 v = ((const float4*)x)[i];
    int base = i * 4;
    int tk = base >> 8, c = base & 255;
    bf16x4 hi = { (__bf16)v.x, (__bf16)v.y, (__bf16)v.z, (__bf16)v.w };
    bf16x4 lo = { (__bf16)(v.x - (float)hi[0]), (__bf16)(v.y - (float)hi[1]),
                  (__bf16)(v.z - (float)hi[2]), (__bf16)(v.w - (float)hi[3]) };
    __bf16* row = xs + (size_t)tk * GK + c;
    *(bf16x4*)(row)       = hi;
    *(bf16x4*)(row + 256) = lo;
    *(bf16x4*)(row + 512) = hi;
  } else if (idx < 2176) {
    // gate weight: transpose + bf16x2 split into B^T layout [n][GK]
    int g = idx - 2048;
    int k0 = (g & 7) * 32, n0 = (g >> 3) * 32;
    #pragma unroll
    for (int j = 0; j < 4; j++) {
      int kl = ty + j * 8;
      t[kl][tx] = gw[(size_t)(k0 + kl) * HID + n0 + tx];
    }
    __syncthreads();
    #pragma unroll
    for (int j = 0; j < 4; j++) {
      int nl = ty + j * 8;
      float v = t[tx][nl];
      __bf16 hi = (__bf16)v;
      __bf16 lo = (__bf16)(v - (float)hi);
      __bf16* drow = gwt + (size_t)(n0 + nl) * GK + k0 + tx;
      drow[0]   = hi;
      drow[256] = hi;
      drow[512] = lo;
    }
  } else {
    // zero the logits accumulator (gate GEMM combines partials via atomicAdd)
    int i = (idx - 2176) * 256 + tid;
    ((float4*)logitz)[i] = make_float4(0.f, 0.f, 0.f, 0.f);
  }
}

// ---- gate GEMM (blocks 0..511) + expert weight transposes (blocks 512..8703) ----
__global__ __launch_bounds__(256) void gate_fused_kernel(
    const __bf16* __restrict__ xs, const __bf16* __restrict__ gwt,
    const float* __restrict__ gate_b, float* __restrict__ logits,
    const float* __restrict__ gow,
    const float* __restrict__ w1, __bf16* __restrict__ w1t,
    const float* __restrict__ w2, __bf16* __restrict__ w2t,
    const float* __restrict__ w3, __bf16* __restrict__ w3t) {
  __shared__ __align__(16) char smem[8192 + 64 * 132 * 4];
  int bx = blockIdx.x;
  int tid = threadIdx.x;

  if (bx >= 512) {
    // ---- transpose-convert roles ----
    float (*t)[33] = (float (*)[33])smem;
    int tx = tid & 31, ty = tid >> 5;
    int g = bx - 512;
    if (g < 2048) {        // w1: K=256 (8), N=512 (16), E=16
      transpose_cvt_body(w1, w1t, DIN, HID, g & 7, (g >> 3) & 15, g >> 7, tx, ty, t);
    } else if (g < 6144) { // w2: K=512 (16), N=512 (16), E=16
      int g2 = g - 2048;
      transpose_cvt_body(w2, w2t, HID, HID, g2 & 15, (g2 >> 4) & 15, g2 >> 8, tx, ty, t);
    } else {               // w3: K=512 (16), N=256 (8), E=16
      int g3 = g - 6144;
      transpose_cvt_body(w3, w3t, HID, DOUT, g3 & 15, (g3 >> 4) & 7, g3 >> 7, tx, ty, t);
    }
    return;
  }

  // ---- gate GEMM role: TM=64, TN=128, BK=32, K=768 ----
  int mt = bx >> 2, nt = bx & 3;
  __bf16* AlB = (__bf16*)smem;           // [2][64][32]
  __bf16* BlB = (__bf16*)(smem + 8192);  // [2][128][32]

  int lane = tid & 63, w = tid >> 6;
  int l16 = lane & 15, quad = lane >> 4;

  int r0 = tid >> 2;
  int q8 = ((tid & 3) ^ ((r0 >> 1) & 3)) * 8;  // slot swizzle (both sides)
  const __bf16* apg  = xs + (size_t)(mt * 64 + r0) * GK + q8;
  const __bf16* bpg0 = gwt + (size_t)(nt * 128 + r0) * GK + q8;
  const __bf16* bpg1 = bpg0 + (size_t)64 * GK;

  __bf16* al0 = AlB;
  __bf16* al1 = AlB + 2048;
  __bf16* bl0 = BlB;
  __bf16* bl1 = BlB + 4096;

  f32x4 acc[4][2];
  #pragma unroll
  for (int i = 0; i < 4; i++)
    #pragma unroll
    for (int j = 0; j < 2; j++) acc[i][j] = {0.f, 0.f, 0.f, 0.f};

  async_cp16(apg, al0 + tid * 8);
  async_cp16(bpg0, bl0 + tid * 8);
  async_cp16(bpg1, bl0 + (tid + 256) * 8);

  int qs = (quad ^ ((l16 >> 1) & 3)) * 8;

  const int nIter = GK >> 5;  // 24
  for (int it = 0; it < nIter; ++it) {
    int buf = it & 1;
    if (it + 1 < nIter) {
      int kb = (it + 1) << 5;
      __bf16* an = buf ? al0 : al1;
      __bf16* bn = buf ? bl0 : bl1;
      async_cp16(apg + kb, an + tid * 8);
      async_cp16(bpg0 + kb, bn + tid * 8);
      async_cp16(bpg1 + kb, bn + (tid + 256) * 8);
      asm volatile("s_waitcnt vmcnt(3)" ::: "memory");
    } else {
      asm volatile("s_waitcnt vmcnt(0)" ::: "memory");
    }
    __builtin_amdgcn_s_barrier();
    asm volatile("" ::: "memory");
    const __bf16* ab = buf ? al1 : al0;
    const __bf16* bb = buf ? bl1 : bl0;
    bf16x8 af[4], bfr[2];
    #pragma unroll
    for (int i = 0; i < 4; i++)
      af[i] = *(const bf16x8*)(ab + (size_t)(i * 16 + l16) * 32 + qs);
    #pragma unroll
    for (int i = 0; i < 2; i++)
      bfr[i] = *(const bf16x8*)(bb + (size_t)(w * 32 + i * 16 + l16) * 32 + qs);
    #pragma unroll
    for (int mi = 0; mi < 4; mi++)
      #pragma unroll
      for (int ni = 0; ni < 2; ni++)
        acc[mi][ni] = __builtin_amdgcn_mfma_f32_16x16x32_bf16(af[mi], bfr[ni], acc[mi][ni], 0, 0, 0);
    asm volatile("" ::: "memory");
    __builtin_amdgcn_s_barrier();
  }

  // ---- fused logits epilogue ----
  __syncthreads();
  float* wl = (float*)smem;              // [128][16]  gate_out_w slice
  float* ht = (float*)(smem + 8192);     // [64][132]  relu'd hidden tile (fp32)
  if (tid < 128) {
    const float* gr = gow + (size_t)(nt * 128 + tid) * 16;
    #pragma unroll
    for (int j = 0; j < 4; j++)
      *(float4*)&wl[tid * 16 + j * 4] = *(const float4*)&gr[j * 4];
  }
  float bv[2];
  #pragma unroll
  for (int ni = 0; ni < 2; ni++) bv[ni] = gate_b[nt * 128 + w * 32 + ni * 16 + l16];
  #pragma unroll
  for (int mi = 0; mi < 4; mi++)
    #pragma unroll
    for (int ni = 0; ni < 2; ni++)
      #pragma unroll
      for (int r = 0; r < 4; r++) {
        int row = mi * 16 + quad * 4 + r;
        int col = w * 32 + ni * 16 + l16;
        ht[row * 132 + col] = fmaxf(acc[mi][ni][r] + bv[ni], 0.f);
      }
  __syncthreads();
  int t = tid >> 2, e4 = (tid & 3) * 4;
  float s0 = 0.f, s1 = 0.f, s2 = 0.f, s3 = 0.f;
  #pragma unroll 4
  for (int h = 0; h < 128; h++) {
    float hv = ht[t * 132 + h];
    const float* wr = &wl[h * 16 + e4];
    s0 = fmaf(hv, wr[0], s0);
    s1 = fmaf(hv, wr[1], s1);
    s2 = fmaf(hv, wr[2], s2);
    s3 = fmaf(hv, wr[3], s3);
  }
  float* lp = logits + (size_t)(mt * 64 + t) * 16 + e4;
  atomicAdd(lp + 0, s0);
  atomicAdd(lp + 1, s1);
  atomicAdd(lp + 2, s2);
  atomicAdd(lp + 3, s3);
}

// ---------------- top-2 + softmax + block-local histogram/ranks ----------------
__global__ __launch_bounds__(256) void top2_kernel(const float* __restrict__ logits,
                                                   const float* __restrict__ gb,
                                                   int2* __restrict__ e01,
                                                   float2* __restrict__ g01,
                                                   int* __restrict__ lrank,
                                                   int* __restrict__ blockhist) {
  __shared__ int hist[NEXP];
  __shared__ float gbl[NEXP];
  int tid = threadIdx.x;
  if (tid < NEXP) { hist[tid] = 0; gbl[tid] = gb[tid]; }
  __syncthreads();
  int t = blockIdx.x * 256 + tid;
  float lv[16];
  const float4* lp = (const float4*)(logits + (size_t)t * 16);
  #pragma unroll
  for (int j = 0; j < 4; j++) {
    float4 v = lp[j];
    lv[4*j]   = v.x + gbl[4*j];
    lv[4*j+1] = v.y + gbl[4*j+1];
    lv[4*j+2] = v.z + gbl[4*j+2];
    lv[4*j+3] = v.w + gbl[4*j+3];
  }
  float v0 = -3.402823466e38f, v1 = -3.402823466e38f;
  int i0 = 0, i1 = 0;
  #pragma unroll
  for (int e = 0; e < 16; e++) {
    float v = lv[e];
    if (v > v0) { v1 = v0; i1 = i0; v0 = v; i0 = e; }
    else if (v > v1) { v1 = v; i1 = e; }
  }
  float ew = expf(v1 - v0);
  float inv = 1.f / (1.f + ew);
  e01[t] = make_int2(i0, i1);
  g01[t] = make_float2(inv, ew * inv);
  int r0 = atomicAdd(&hist[i0], 1);
  int r1 = atomicAdd(&hist[i1], 1);
  lrank[2 * t]     = r0;
  lrank[2 * t + 1] = r1;
  __syncthreads();
  if (tid < NEXP) blockhist[blockIdx.x * NEXP + tid] = hist[tid];
}

// ------ fill + redundant scan: each block recomputes the small scan in LDS; block 0
// additionally writes offsets + flat tile list. ------
__global__ __launch_bounds__(256) void fillscan_kernel(const int2* __restrict__ e01,
                                                       const int* __restrict__ lrank,
                                                       const int* __restrict__ blockhist,
                                                       int* __restrict__ tok_sorted,
                                                       int* __restrict__ route_pos,
                                                       int* __restrict__ offsets,
                                                       int* __restrict__ tile_e,
                                                       int* __restrict__ tile_mt,
                                                       int* __restrict__ ntiles) {
  __shared__ int tot_s[NEXP], pre_s[NEXP], soff[NEXP + 1], base_l[NEXP], tbase[NEXP];
  int b = blockIdx.x;
  int tid = threadIdx.x;
  if (tid < NEXP) {
    int s_all = 0, s_pre = 0;
    for (int bb = 0; bb < NBLK; bb++) {
      int h = blockhist[bb * NEXP + tid];
      s_pre += (bb < b) ? h : 0;
      s_all += h;
    }
    tot_s[tid] = s_all;
    pre_s[tid] = s_pre;
  }
  __syncthreads();
  if (tid == 0) {
    int s = 0, tb = 0;
    for (int i = 0; i < NEXP; i++) {
      soff[i] = s; s += tot_s[i];
      tbase[i] = tb; tb += (tot_s[i] + 63) >> 6;
    }
    soff[NEXP] = s;
    if (b == 0) *ntiles = tb;
  }
  __syncthreads();
  if (tid < NEXP) base_l[tid] = soff[tid] + pre_s[tid];
  if (b == 0) {
    if (tid < NEXP + 1) offsets[tid] = soff[tid];
    if (tid < NEXP) {
      int nt = (tot_s[tid] + 63) >> 6, tb0 = tbase[tid];
      for (int m = 0; m < nt; m++) { tile_e[tb0 + m] = tid; tile_mt[tb0 + m] = m; }
    }
  }
  __syncthreads();
  int t = b * 256 + tid;
  int2 e = e01[t];
  int p0 = base_l[e.x] + lrank[2 * t];
  int p1 = base_l[e.y] + lrank[2 * t + 1];
  tok_sorted[p0] = t; route_pos[2 * t]     = p0;
  tok_sorted[p1] = t; route_pos[2 * t + 1] = p1;
}

// ------- grouped expert GEMM: TM=64, TN=128, BK=64 (16 MFMA / barrier-pair / wave),
// dbuf async LDS (48KB -> 3 blocks/CU), XCD-chunked tile list, 8-slot swizzle.
// bf16 store; LDA separate from K so GEMM1 reads the hi block of xs (LDA=GK).
template<bool RELU>
__global__ __launch_bounds__(256) void moe_gemm_kernel(const __bf16* __restrict__ A,
                                                       const __bf16* __restrict__ Bt,
                                                       const float* __restrict__ bias,
                                                       __bf16* __restrict__ out,
                                                       const int* __restrict__ seg_off,
                                                       const int* __restrict__ gather,
                                                       const int* __restrict__ tile_e,
                                                       const int* __restrict__ tile_mt,
                                                       const int* __restrict__ ntiles,
                                                       int LDA, int K, int N) {
  // XCD chunk swizzle: 272 = 8 * 34; XCD(bid)≈bid%8 -> tiles [x*34, x*34+34) per XCD.
  int bx0 = blockIdx.x;
  int bx = (bx0 & 7) * (MAXTILE >> 3) + (bx0 >> 3);
  if (bx >= *ntiles) return;
  int e  = tile_e[bx];
  int mt = tile_mt[bx];
  int off = seg_off[e];
  int Te  = seg_off[e + 1] - off;
  int nt = blockIdx.y;

  __shared__ __align__(16) char smem[49152];
  __bf16* AlB = (__bf16*)smem;            // [2][64][64]  (16 KB)
  __bf16* BlB = (__bf16*)(smem + 16384);  // [2][128][64] (32 KB)

  int tid = threadIdx.x;
  int lane = tid & 63, w = tid >> 6;
  int l16 = lane & 15, quad = lane >> 4;

  int r0 = tid >> 3;                        // staging row 0..31
  int q8 = ((tid & 7) ^ (r0 & 7)) * 8;      // 8-slot swizzle (both sides; +32k rows keep xor)
  int rowA0 = mt * 64 + r0;
  int rowA1 = rowA0 + 32;
  int rA0 = rowA0 < Te ? rowA0 : Te - 1;
  int rA1 = rowA1 < Te ? rowA1 : Te - 1;
  size_t ga0 = gather ? (size_t)gather[off + rA0] : (size_t)(off + rA0);
  size_t ga1 = gather ? (size_t)gather[off + rA1] : (size_t)(off + rA1);
  const __bf16* apg0 = A + ga0 * LDA + q8;
  const __bf16* apg1 = A + ga1 * LDA + q8;
  const __bf16* Bte  = Bt + (size_t)e * N * K;
  const __bf16* bpg0 = Bte + (size_t)(nt * 128 + r0) * K + q8;
  const __bf16* bpg1 = bpg0 + (size_t)32 * K;
  const __bf16* bpg2 = bpg0 + (size_t)64 * K;
  const __bf16* bpg3 = bpg0 + (size_t)96 * K;

  __bf16* al0 = AlB;
  __bf16* al1 = AlB + 4096;
  __bf16* bl0 = BlB;
  __bf16* bl1 = BlB + 8192;

  f32x4 acc[4][2];
  #pragma unroll
  for (int i = 0; i < 4; i++)
    #pragma unroll
    for (int j = 0; j < 2; j++) acc[i][j] = {0.f, 0.f, 0.f, 0.f};

  async_cp16(apg0, al0 + tid * 8);
  async_cp16(apg1, al0 + (tid + 256) * 8);
  async_cp16(bpg0, bl0 + tid * 8);
  async_cp16(bpg1, bl0 + (tid + 256) * 8);
  async_cp16(bpg2, bl0 + (tid + 512) * 8);
  async_cp16(bpg3, bl0 + (tid + 768) * 8);

  int x7 = (l16 & 7);                       // read-side xor (row ≡ l16 mod 8)

  int nIter = K >> 6;
  for (int it = 0; it < nIter; ++it) {
    int buf = it & 1;
    if (it + 1 < nIter) {
      int kb = (it + 1) << 6;
      __bf16* an = buf ? al0 : al1;
      __bf16* bn = buf ? bl0 : bl1;
      async_cp16(apg0 + kb, an + tid * 8);
      async_cp16(apg1 + kb, an + (tid + 256) * 8);
      async_cp16(bpg0 + kb, bn + tid * 8);
      async_cp16(bpg1 + kb, bn + (tid + 256) * 8);
      async_cp16(bpg2 + kb, bn + (tid + 512) * 8);
      async_cp16(bpg3 + kb, bn + (tid + 768) * 8);
      asm volatile("s_waitcnt vmcnt(6)" ::: "memory");
    } else {
      asm volatile("s_waitcnt vmcnt(0)" ::: "memory");
    }
    __builtin_amdgcn_s_barrier();
    asm volatile("" ::: "memory");
    const __bf16* ab = buf ? al1 : al0;
    const __bf16* bb = buf ? bl1 : bl0;
    #pragma unroll
    for (int kk = 0; kk < 2; kk++) {
      int qs = ((kk * 4 + quad) ^ x7) * 8;
      bf16x8 af[4], bfr[2];
      #pragma unroll
      for (int i = 0; i < 4; i++)
        af[i] = *(const bf16x8*)(ab + (size_t)(i * 16 + l16) * 64 + qs);
      #pragma unroll
      for (int i = 0; i < 2; i++)
        bfr[i] = *(const bf16x8*)(bb + (size_t)(w * 32 + i * 16 + l16) * 64 + qs);
      #pragma unroll
      for (int mi = 0; mi < 4; mi++)
        #pragma unroll
        for (int ni = 0; ni < 2; ni++)
          acc[mi][ni] = __builtin_amdgcn_mfma_f32_16x16x32_bf16(af[mi], bfr[ni], acc[mi][ni], 0, 0, 0);
    }
    asm volatile("" ::: "memory");
    __builtin_amdgcn_s_barrier();
  }

  const float* be = bias + (size_t)e * N;
  #pragma unroll
  for (int ni = 0; ni < 2; ni++) {
    int col = nt * 128 + w * 32 + ni * 16 + l16;
    float bv = be[col];
    #pragma unroll
    for (int mi = 0; mi < 4; mi++) {
      #pragma unroll
      for (int r = 0; r < 4; r++) {
        int row_in = mt * 64 + mi * 16 + quad * 4 + r;
        if (row_in < Te) {
          float v = acc[mi][ni][r] + bv;
          if (RELU) v = fmaxf(v, 0.f);
          out[(size_t)(off + row_in) * N + col] = (__bf16)v;
        }
      }
    }
  }
}

// ---------------- final combine: out[t] = g0*Y[p0] + g1*Y[p1]  (Y in bf16) ----------------
__global__ void combine_kernel(const __bf16* __restrict__ Y, const int* __restrict__ route_pos,
                               const float2* __restrict__ g01, float* __restrict__ out) {
  int gid = blockIdx.x * blockDim.x + threadIdx.x;
  int t = gid >> 6, c = (gid & 63) << 2;
  if (t >= NTOK) return;
  int p0 = route_pos[2 * t], p1 = route_pos[2 * t + 1];
  float2 g = g01[t];
  bf16x4 y0 = *(const bf16x4*)&Y[(size_t)p0 * DOUT + c];
  bf16x4 y1 = *(const bf16x4*)&Y[(size_t)p1 * DOUT + c];
  float4 o;
  o.x = g.x * (float)y0[0] + g.y * (float)y1[0];
  o.y = g.x * (float)y0[1] + g.y * (float)y1[1];
  o.z = g.x * (float)y0[2] + g.y * (float)y1[2];
  o.w = g.x * (float)y0[3] + g.y * (float)y1[3];
  *(float4*)&out[(size_t)t * DOUT + c] = o;
}

// ---------------- launcher ----------------
extern "C" void kernel_launch(void* const* d_in, const int* in_sizes, int n_in,
                              void* d_out, int out_size, void* d_ws, size_t ws_size,
                              hipStream_t stream) {
  const float* x          = (const float*)d_in[0];
  const float* gate_w     = (const float*)d_in[1];
  const float* gate_b     = (const float*)d_in[2];
  const float* gate_out_w = (const float*)d_in[3];
  const float* gate_out_b = (const float*)d_in[4];
  const float* w1         = (const float*)d_in[5];
  const float* b1         = (const float*)d_in[6];
  const float* w2         = (const float*)d_in[7];
  const float* b2         = (const float*)d_in[8];
  const float* w3         = (const float*)d_in[9];
  const float* b3         = (const float*)d_in[10];
  float* out = (float*)d_out;

  char* ws = (char*)d_ws;
  size_t o = 0;
  auto alloc = [&](size_t bytes) -> void* {
    o = (o + 255) & ~(size_t)255;
    void* p = ws + o;
    o += bytes;
    return p;
  };

  __bf16* w1t  = (__bf16*)alloc((size_t)NEXP * HID * DIN * 2);
  __bf16* w2t  = (__bf16*)alloc((size_t)NEXP * HID * HID * 2);
  __bf16* w3t  = (__bf16*)alloc((size_t)NEXP * DOUT * HID * 2);
  __bf16* gwt  = (__bf16*)alloc((size_t)HID * GK * 2);
  __bf16* H1   = (__bf16*)alloc((size_t)(NKA + 128) * HID * 2);
  // xs (gate split input + GEMM1 hi input; dead after GEMM1) aliases H2
  size_t r3 = (size_t)NTOK * GK * 2;
  size_t r4 = (size_t)(NKA + 128) * HID * 2;
  void* region2 = alloc(r3 > r4 ? r3 : r4);
  __bf16* xs = (__bf16*)region2;
  __bf16* H2 = (__bf16*)region2;
  float* logits    = (float*)alloc((size_t)NTOK * 16 * 4);
  int2*  e01       = (int2*)alloc((size_t)NTOK * 8);
  float2* g01      = (float2*)alloc((size_t)NTOK * 8);
  int*   offsets   = (int*)alloc((NEXP + 1) * 4);
  int*   blockhist = (int*)alloc((size_t)NBLK * NEXP * 4);
  int*   lrank     = (int*)alloc((size_t)NTOK * 2 * 4);
  int*   tok_sorted= (int*)alloc((size_t)(NKA + 128) * 4);
  int*   route_pos = (int*)alloc((size_t)NTOK * 2 * 4);
  int*   tile_e    = (int*)alloc(MAXTILE * 4);
  int*   tile_mt   = (int*)alloc(MAXTILE * 4);
  int*   ntiles    = (int*)alloc(4);
  __bf16* Y        = (__bf16*)alloc((size_t)(NKA + 128) * DOUT * 2);
  (void)ws_size; (void)n_in; (void)in_sizes; (void)out_size;

  // 1. prep (x split + gate weight split + zero(logits))
  prep_kernel<<<2304, 256, 0, stream>>>(x, xs, gate_w, gwt, logits);

  // 2. gate GEMM + fused logits epilogue, with expert-weight transposes riding along
  gate_fused_kernel<<<8704, 256, 0, stream>>>(xs, gwt, gate_b, logits, gate_out_w,
                                              w1, w1t, w2, w2t, w3, w3t);

  // 3-4. top-2 routing, then fill+scan
  top2_kernel<<<NBLK, 256, 0, stream>>>(logits, gate_out_b, e01, g01, lrank, blockhist);
  fillscan_kernel<<<NBLK, 256, 0, stream>>>(e01, lrank, blockhist, tok_sorted, route_pos,
                                            offsets, tile_e, tile_mt, ntiles);

  // 5-7. expert GEMMs (BK=64; GEMM1 reads the hi block of xs via LDA=GK)
  moe_gemm_kernel<true><<<dim3(MAXTILE, HID / 128), 256, 0, stream>>>(
      xs, w1t, b1, H1, offsets, tok_sorted, tile_e, tile_mt, ntiles, GK, DIN, HID);
  moe_gemm_kernel<true><<<dim3(MAXTILE, HID / 128), 256, 0, stream>>>(
      H1, w2t, b2, H2, offsets, nullptr, tile_e, tile_mt, ntiles, HID, HID, HID);
  moe_gemm_kernel<false><<<dim3(MAXTILE, DOUT / 128), 256, 0, stream>>>(
      H2, w3t, b3, Y, offsets, nullptr, tile_e, tile_mt, ntiles, HID, HID, DOUT);

  // 8. combine (bf16 Y)
  combine_kernel<<<(NTOK * 64) / 256, 256, 0, stream>>>(Y, route_pos, g01, out);
}

// Round 12
// 190.949 us; speedup vs baseline: 1.0675x; 1.0156x over previous
//
#include <hip/hip_runtime.h>
#include <hip/hip_bf16.h>
#include <stdint.h>

#define NTOK 8192
#define DIN  256
#define DOUT 256
#define NEXP 16
#define HID  512
#define NKA  (NTOK*2)    // total assignments
#define NBLK (NTOK/256)  // routing/fill blocks (256 tokens each)
#define MAXTILE 272      // sum ceil(Te/64) <= 16384/64 + 16  (= 8*34, XCD-swizzle friendly)
#define GK 768           // gate split-GEMM K: [x_hi | x_lo | x_hi]

typedef __bf16 bf16x8 __attribute__((ext_vector_type(8)));
typedef __bf16 bf16x4 __attribute__((ext_vector_type(4)));
typedef float  f32x4  __attribute__((ext_vector_type(4)));

// async 16B global -> LDS (DMA; wave-uniform LDS base + lane*16)
__device__ __forceinline__ void async_cp16(const __bf16* g, __bf16* l) {
  __builtin_amdgcn_global_load_lds(
      (const __attribute__((address_space(1))) unsigned int*)g,
      (__attribute__((address_space(3))) unsigned int*)l, 16, 0, 0);
}

// ------------- shared transpose body: src[k][e][n] fp32 -> dst[e][n][k] bf16 -------------
__device__ __forceinline__ void transpose_cvt_body(const float* __restrict__ src,
                                                   __bf16* __restrict__ dst,
                                                   int K, int N, int bx, int by, int bz,
                                                   int tx, int ty, float (*t)[33]) {
  int e = bz, k0 = bx * 32, n0 = by * 32;
  #pragma unroll
  for (int j = 0; j < 4; j++) {
    int kl = ty + j * 8;
    t[kl][tx] = src[(size_t)(k0 + kl) * (NEXP * N) + (size_t)e * N + n0 + tx];
  }
  __syncthreads();
  #pragma unroll
  for (int j = 0; j < 4; j++) {
    int nl = ty + j * 8;
    dst[(size_t)e * N * K + (size_t)(n0 + nl) * K + k0 + tx] = (__bf16)t[tx][nl];
  }
}

// ---------------- prep: x bf16x2 split + gate weight split + zero(logits) ----------------
__global__ __launch_bounds__(256) void prep_kernel(
    const float* __restrict__ x, __bf16* __restrict__ xs,
    const float* __restrict__ gw, __bf16* __restrict__ gwt,
    float* __restrict__ logitz) {
  __shared__ float t[32][33];
  int idx = blockIdx.x;
  int tid = threadIdx.x;
  int tx = tid & 31, ty = tid >> 5;
  if (idx < 2048) {
    // cvt_x: fp32 -> bf16x2 split rows [hi | lo | hi]  (hi block doubles as GEMM1 input)
    int i = idx * 256 + tid;
    float4 v = ((const float4*)x)[i];
    int base = i * 4;
    int tk = base >> 8, c = base & 255;
    bf16x4 hi = { (__bf16)v.x, (__bf16)v.y, (__bf16)v.z, (__bf16)v.w };
    bf16x4 lo = { (__bf16)(v.x - (float)hi[0]), (__bf16)(v.y - (float)hi[1]),
                  (__bf16)(v.z - (float)hi[2]), (__bf16)(v.w - (float)hi[3]) };
    __bf16* row = xs + (size_t)tk * GK + c;
    *(bf16x4*)(row)       = hi;
    *(bf16x4*)(row + 256) = lo;
    *(bf16x4*)(row + 512) = hi;
  } else if (idx < 2176) {
    // gate weight: transpose + bf16x2 split into B^T layout [n][GK]
    int g = idx - 2048;
    int k0 = (g & 7) * 32, n0 = (g >> 3) * 32;
    #pragma unroll
    for (int j = 0; j < 4; j++) {
      int kl = ty + j * 8;
      t[kl][tx] = gw[(size_t)(k0 + kl) * HID + n0 + tx];
    }
    __syncthreads();
    #pragma unroll
    for (int j = 0; j < 4; j++) {
      int nl = ty + j * 8;
      float v = t[tx][nl];
      __bf16 hi = (__bf16)v;
      __bf16 lo = (__bf16)(v - (float)hi);
      __bf16* drow = gwt + (size_t)(n0 + nl) * GK + k0 + tx;
      drow[0]   = hi;
      drow[256] = hi;
      drow[512] = lo;
    }
  } else {
    // zero the logits accumulator (gate GEMM combines partials via atomicAdd)
    int i = (idx - 2176) * 256 + tid;
    ((float4*)logitz)[i] = make_float4(0.f, 0.f, 0.f, 0.f);
  }
}

// ---- gate GEMM (blocks 0..511, BK=64) + expert weight transposes (blocks 512..8703) ----
__global__ __launch_bounds__(256) void gate_fused_kernel(
    const __bf16* __restrict__ xs, const __bf16* __restrict__ gwt,
    const float* __restrict__ gate_b, float* __restrict__ logits,
    const float* __restrict__ gow,
    const float* __restrict__ w1, __bf16* __restrict__ w1t,
    const float* __restrict__ w2, __bf16* __restrict__ w2t,
    const float* __restrict__ w3, __bf16* __restrict__ w3t) {
  __shared__ __align__(16) char smem[49152];
  int bx = blockIdx.x;
  int tid = threadIdx.x;

  if (bx >= 512) {
    // ---- transpose-convert roles ----
    float (*t)[33] = (float (*)[33])smem;
    int tx = tid & 31, ty = tid >> 5;
    int g = bx - 512;
    if (g < 2048) {        // w1: K=256 (8), N=512 (16), E=16
      transpose_cvt_body(w1, w1t, DIN, HID, g & 7, (g >> 3) & 15, g >> 7, tx, ty, t);
    } else if (g < 6144) { // w2: K=512 (16), N=512 (16), E=16
      int g2 = g - 2048;
      transpose_cvt_body(w2, w2t, HID, HID, g2 & 15, (g2 >> 4) & 15, g2 >> 8, tx, ty, t);
    } else {               // w3: K=512 (16), N=256 (8), E=16
      int g3 = g - 6144;
      transpose_cvt_body(w3, w3t, HID, DOUT, g3 & 15, (g3 >> 4) & 7, g3 >> 7, tx, ty, t);
    }
    return;
  }

  // ---- gate GEMM role: TM=64, TN=128, BK=64, K=768 (12 barrier-pair iters) ----
  int mt = bx >> 2, nt = bx & 3;
  __bf16* AlB = (__bf16*)smem;            // [2][64][64]  (16 KB)
  __bf16* BlB = (__bf16*)(smem + 16384);  // [2][128][64] (32 KB)

  int lane = tid & 63, w = tid >> 6;
  int l16 = lane & 15, quad = lane >> 4;

  int r0 = tid >> 3;                      // staging row 0..31
  int q8 = ((tid & 7) ^ (r0 & 7)) * 8;    // 8-slot swizzle (both sides; +32k rows keep xor)
  const __bf16* apg0 = xs + (size_t)(mt * 64 + r0) * GK + q8;
  const __bf16* apg1 = apg0 + (size_t)32 * GK;
  const __bf16* bpg0 = gwt + (size_t)(nt * 128 + r0) * GK + q8;
  const __bf16* bpg1 = bpg0 + (size_t)32 * GK;
  const __bf16* bpg2 = bpg0 + (size_t)64 * GK;
  const __bf16* bpg3 = bpg0 + (size_t)96 * GK;

  __bf16* al0 = AlB;
  __bf16* al1 = AlB + 4096;
  __bf16* bl0 = BlB;
  __bf16* bl1 = BlB + 8192;

  f32x4 acc[4][2];
  #pragma unroll
  for (int i = 0; i < 4; i++)
    #pragma unroll
    for (int j = 0; j < 2; j++) acc[i][j] = {0.f, 0.f, 0.f, 0.f};

  async_cp16(apg0, al0 + tid * 8);
  async_cp16(apg1, al0 + (tid + 256) * 8);
  async_cp16(bpg0, bl0 + tid * 8);
  async_cp16(bpg1, bl0 + (tid + 256) * 8);
  async_cp16(bpg2, bl0 + (tid + 512) * 8);
  async_cp16(bpg3, bl0 + (tid + 768) * 8);

  int x7 = (l16 & 7);                     // read-side xor (row ≡ l16 mod 8)

  const int nIter = GK >> 6;  // 12
  for (int it = 0; it < nIter; ++it) {
    int buf = it & 1;
    if (it + 1 < nIter) {
      int kb = (it + 1) << 6;
      __bf16* an = buf ? al0 : al1;
      __bf16* bn = buf ? bl0 : bl1;
      async_cp16(apg0 + kb, an + tid * 8);
      async_cp16(apg1 + kb, an + (tid + 256) * 8);
      async_cp16(bpg0 + kb, bn + tid * 8);
      async_cp16(bpg1 + kb, bn + (tid + 256) * 8);
      async_cp16(bpg2 + kb, bn + (tid + 512) * 8);
      async_cp16(bpg3 + kb, bn + (tid + 768) * 8);
      asm volatile("s_waitcnt vmcnt(6)" ::: "memory");
    } else {
      asm volatile("s_waitcnt vmcnt(0)" ::: "memory");
    }
    __builtin_amdgcn_s_barrier();
    asm volatile("" ::: "memory");
    const __bf16* ab = buf ? al1 : al0;
    const __bf16* bb = buf ? bl1 : bl0;
    #pragma unroll
    for (int kk = 0; kk < 2; kk++) {
      int qs = ((kk * 4 + quad) ^ x7) * 8;
      bf16x8 af[4], bfr[2];
      #pragma unroll
      for (int i = 0; i < 4; i++)
        af[i] = *(const bf16x8*)(ab + (size_t)(i * 16 + l16) * 64 + qs);
      #pragma unroll
      for (int i = 0; i < 2; i++)
        bfr[i] = *(const bf16x8*)(bb + (size_t)(w * 32 + i * 16 + l16) * 64 + qs);
      #pragma unroll
      for (int mi = 0; mi < 4; mi++)
        #pragma unroll
        for (int ni = 0; ni < 2; ni++)
          acc[mi][ni] = __builtin_amdgcn_mfma_f32_16x16x32_bf16(af[mi], bfr[ni], acc[mi][ni], 0, 0, 0);
    }
    asm volatile("" ::: "memory");
    __builtin_amdgcn_s_barrier();
  }

  // ---- fused logits epilogue ----
  __syncthreads();
  float* wl = (float*)smem;              // [128][16]  gate_out_w slice
  float* ht = (float*)(smem + 8192);     // [64][132]  relu'd hidden tile (fp32)
  if (tid < 128) {
    const float* gr = gow + (size_t)(nt * 128 + tid) * 16;
    #pragma unroll
    for (int j = 0; j < 4; j++)
      *(float4*)&wl[tid * 16 + j * 4] = *(const float4*)&gr[j * 4];
  }
  float bv[2];
  #pragma unroll
  for (int ni = 0; ni < 2; ni++) bv[ni] = gate_b[nt * 128 + w * 32 + ni * 16 + l16];
  #pragma unroll
  for (int mi = 0; mi < 4; mi++)
    #pragma unroll
    for (int ni = 0; ni < 2; ni++)
      #pragma unroll
      for (int r = 0; r < 4; r++) {
        int row = mi * 16 + quad * 4 + r;
        int col = w * 32 + ni * 16 + l16;
        ht[row * 132 + col] = fmaxf(acc[mi][ni][r] + bv[ni], 0.f);
      }
  __syncthreads();
  int t = tid >> 2, e4 = (tid & 3) * 4;
  float s0 = 0.f, s1 = 0.f, s2 = 0.f, s3 = 0.f;
  #pragma unroll 4
  for (int h = 0; h < 128; h++) {
    float hv = ht[t * 132 + h];
    const float* wr = &wl[h * 16 + e4];
    s0 = fmaf(hv, wr[0], s0);
    s1 = fmaf(hv, wr[1], s1);
    s2 = fmaf(hv, wr[2], s2);
    s3 = fmaf(hv, wr[3], s3);
  }
  float* lp = logits + (size_t)(mt * 64 + t) * 16 + e4;
  atomicAdd(lp + 0, s0);
  atomicAdd(lp + 1, s1);
  atomicAdd(lp + 2, s2);
  atomicAdd(lp + 3, s3);
}

// ---------------- top-2 + softmax + block-local histogram/ranks ----------------
__global__ __launch_bounds__(256) void top2_kernel(const float* __restrict__ logits,
                                                   const float* __restrict__ gb,
                                                   int2* __restrict__ e01,
                                                   float2* __restrict__ g01,
                                                   int* __restrict__ lrank,
                                                   int* __restrict__ blockhist) {
  __shared__ int hist[NEXP];
  __shared__ float gbl[NEXP];
  int tid = threadIdx.x;
  if (tid < NEXP) { hist[tid] = 0; gbl[tid] = gb[tid]; }
  __syncthreads();
  int t = blockIdx.x * 256 + tid;
  float lv[16];
  const float4* lp = (const float4*)(logits + (size_t)t * 16);
  #pragma unroll
  for (int j = 0; j < 4; j++) {
    float4 v = lp[j];
    lv[4*j]   = v.x + gbl[4*j];
    lv[4*j+1] = v.y + gbl[4*j+1];
    lv[4*j+2] = v.z + gbl[4*j+2];
    lv[4*j+3] = v.w + gbl[4*j+3];
  }
  float v0 = -3.402823466e38f, v1 = -3.402823466e38f;
  int i0 = 0, i1 = 0;
  #pragma unroll
  for (int e = 0; e < 16; e++) {
    float v = lv[e];
    if (v > v0) { v1 = v0; i1 = i0; v0 = v; i0 = e; }
    else if (v > v1) { v1 = v; i1 = e; }
  }
  float ew = expf(v1 - v0);
  float inv = 1.f / (1.f + ew);
  e01[t] = make_int2(i0, i1);
  g01[t] = make_float2(inv, ew * inv);
  int r0 = atomicAdd(&hist[i0], 1);
  int r1 = atomicAdd(&hist[i1], 1);
  lrank[2 * t]     = r0;
  lrank[2 * t + 1] = r1;
  __syncthreads();
  if (tid < NEXP) blockhist[blockIdx.x * NEXP + tid] = hist[tid];
}

// ------ fill + redundant scan: each block recomputes the small scan in LDS; block 0
// additionally writes offsets + flat tile list. ------
__global__ __launch_bounds__(256) void fillscan_kernel(const int2* __restrict__ e01,
                                                       const int* __restrict__ lrank,
                                                       const int* __restrict__ blockhist,
                                                       int* __restrict__ tok_sorted,
                                                       int* __restrict__ route_pos,
                                                       int* __restrict__ offsets,
                                                       int* __restrict__ tile_e,
                                                       int* __restrict__ tile_mt,
                                                       int* __restrict__ ntiles) {
  __shared__ int tot_s[NEXP], pre_s[NEXP], soff[NEXP + 1], base_l[NEXP], tbase[NEXP];
  int b = blockIdx.x;
  int tid = threadIdx.x;
  if (tid < NEXP) {
    int s_all = 0, s_pre = 0;
    for (int bb = 0; bb < NBLK; bb++) {
      int h = blockhist[bb * NEXP + tid];
      s_pre += (bb < b) ? h : 0;
      s_all += h;
    }
    tot_s[tid] = s_all;
    pre_s[tid] = s_pre;
  }
  __syncthreads();
  if (tid == 0) {
    int s = 0, tb = 0;
    for (int i = 0; i < NEXP; i++) {
      soff[i] = s; s += tot_s[i];
      tbase[i] = tb; tb += (tot_s[i] + 63) >> 6;
    }
    soff[NEXP] = s;
    if (b == 0) *ntiles = tb;
  }
  __syncthreads();
  if (tid < NEXP) base_l[tid] = soff[tid] + pre_s[tid];
  if (b == 0) {
    if (tid < NEXP + 1) offsets[tid] = soff[tid];
    if (tid < NEXP) {
      int nt = (tot_s[tid] + 63) >> 6, tb0 = tbase[tid];
      for (int m = 0; m < nt; m++) { tile_e[tb0 + m] = tid; tile_mt[tb0 + m] = m; }
    }
  }
  __syncthreads();
  int t = b * 256 + tid;
  int2 e = e01[t];
  int p0 = base_l[e.x] + lrank[2 * t];
  int p1 = base_l[e.y] + lrank[2 * t + 1];
  tok_sorted[p0] = t; route_pos[2 * t]     = p0;
  tok_sorted[p1] = t; route_pos[2 * t + 1] = p1;
}

// ------- grouped expert GEMM: TM=64, TN=128, BK=64 (16 MFMA / barrier-pair / wave),
// dbuf async LDS (48KB -> 3 blocks/CU), XCD-chunked tile list, 8-slot swizzle.
// bf16 store; LDA separate from K so GEMM1 reads the hi block of xs (LDA=GK).
template<bool RELU>
__global__ __launch_bounds__(256) void moe_gemm_kernel(const __bf16* __restrict__ A,
                                                       const __bf16* __restrict__ Bt,
                                                       const float* __restrict__ bias,
                                                       __bf16* __restrict__ out,
                                                       const int* __restrict__ seg_off,
                                                       const int* __restrict__ gather,
                                                       const int* __restrict__ tile_e,
                                                       const int* __restrict__ tile_mt,
                                                       const int* __restrict__ ntiles,
                                                       int LDA, int K, int N) {
  // XCD chunk swizzle: 272 = 8 * 34; XCD(bid)≈bid%8 -> tiles [x*34, x*34+34) per XCD.
  int bx0 = blockIdx.x;
  int bx = (bx0 & 7) * (MAXTILE >> 3) + (bx0 >> 3);
  if (bx >= *ntiles) return;
  int e  = tile_e[bx];
  int mt = tile_mt[bx];
  int off = seg_off[e];
  int Te  = seg_off[e + 1] - off;
  int nt = blockIdx.y;

  __shared__ __align__(16) char smem[49152];
  __bf16* AlB = (__bf16*)smem;            // [2][64][64]  (16 KB)
  __bf16* BlB = (__bf16*)(smem + 16384);  // [2][128][64] (32 KB)

  int tid = threadIdx.x;
  int lane = tid & 63, w = tid >> 6;
  int l16 = lane & 15, quad = lane >> 4;

  int r0 = tid >> 3;                        // staging row 0..31
  int q8 = ((tid & 7) ^ (r0 & 7)) * 8;      // 8-slot swizzle (both sides; +32k rows keep xor)
  int rowA0 = mt * 64 + r0;
  int rowA1 = rowA0 + 32;
  int rA0 = rowA0 < Te ? rowA0 : Te - 1;
  int rA1 = rowA1 < Te ? rowA1 : Te - 1;
  size_t ga0 = gather ? (size_t)gather[off + rA0] : (size_t)(off + rA0);
  size_t ga1 = gather ? (size_t)gather[off + rA1] : (size_t)(off + rA1);
  const __bf16* apg0 = A + ga0 * LDA + q8;
  const __bf16* apg1 = A + ga1 * LDA + q8;
  const __bf16* Bte  = Bt + (size_t)e * N * K;
  const __bf16* bpg0 = Bte + (size_t)(nt * 128 + r0) * K + q8;
  const __bf16* bpg1 = bpg0 + (size_t)32 * K;
  const __bf16* bpg2 = bpg0 + (size_t)64 * K;
  const __bf16* bpg3 = bpg0 + (size_t)96 * K;

  __bf16* al0 = AlB;
  __bf16* al1 = AlB + 4096;
  __bf16* bl0 = BlB;
  __bf16* bl1 = BlB + 8192;

  f32x4 acc[4][2];
  #pragma unroll
  for (int i = 0; i < 4; i++)
    #pragma unroll
    for (int j = 0; j < 2; j++) acc[i][j] = {0.f, 0.f, 0.f, 0.f};

  async_cp16(apg0, al0 + tid * 8);
  async_cp16(apg1, al0 + (tid + 256) * 8);
  async_cp16(bpg0, bl0 + tid * 8);
  async_cp16(bpg1, bl0 + (tid + 256) * 8);
  async_cp16(bpg2, bl0 + (tid + 512) * 8);
  async_cp16(bpg3, bl0 + (tid + 768) * 8);

  int x7 = (l16 & 7);                       // read-side xor (row ≡ l16 mod 8)

  int nIter = K >> 6;
  for (int it = 0; it < nIter; ++it) {
    int buf = it & 1;
    if (it + 1 < nIter) {
      int kb = (it + 1) << 6;
      __bf16* an = buf ? al0 : al1;
      __bf16* bn = buf ? bl0 : bl1;
      async_cp16(apg0 + kb, an + tid * 8);
      async_cp16(apg1 + kb, an + (tid + 256) * 8);
      async_cp16(bpg0 + kb, bn + tid * 8);
      async_cp16(bpg1 + kb, bn + (tid + 256) * 8);
      async_cp16(bpg2 + kb, bn + (tid + 512) * 8);
      async_cp16(bpg3 + kb, bn + (tid + 768) * 8);
      asm volatile("s_waitcnt vmcnt(6)" ::: "memory");
    } else {
      asm volatile("s_waitcnt vmcnt(0)" ::: "memory");
    }
    __builtin_amdgcn_s_barrier();
    asm volatile("" ::: "memory");
    const __bf16* ab = buf ? al1 : al0;
    const __bf16* bb = buf ? bl1 : bl0;
    #pragma unroll
    for (int kk = 0; kk < 2; kk++) {
      int qs = ((kk * 4 + quad) ^ x7) * 8;
      bf16x8 af[4], bfr[2];
      #pragma unroll
      for (int i = 0; i < 4; i++)
        af[i] = *(const bf16x8*)(ab + (size_t)(i * 16 + l16) * 64 + qs);
      #pragma unroll
      for (int i = 0; i < 2; i++)
        bfr[i] = *(const bf16x8*)(bb + (size_t)(w * 32 + i * 16 + l16) * 64 + qs);
      #pragma unroll
      for (int mi = 0; mi < 4; mi++)
        #pragma unroll
        for (int ni = 0; ni < 2; ni++)
          acc[mi][ni] = __builtin_amdgcn_mfma_f32_16x16x32_bf16(af[mi], bfr[ni], acc[mi][ni], 0, 0, 0);
    }
    asm volatile("" ::: "memory");
    __builtin_amdgcn_s_barrier();
  }

  const float* be = bias + (size_t)e * N;
  #pragma unroll
  for (int ni = 0; ni < 2; ni++) {
    int col = nt * 128 + w * 32 + ni * 16 + l16;
    float bv = be[col];
    #pragma unroll
    for (int mi = 0; mi < 4; mi++) {
      #pragma unroll
      for (int r = 0; r < 4; r++) {
        int row_in = mt * 64 + mi * 16 + quad * 4 + r;
        if (row_in < Te) {
          float v = acc[mi][ni][r] + bv;
          if (RELU) v = fmaxf(v, 0.f);
          out[(size_t)(off + row_in) * N + col] = (__bf16)v;
        }
      }
    }
  }
}

// ---------------- final combine: out[t] = g0*Y[p0] + g1*Y[p1]  (Y in bf16) ----------------
__global__ void combine_kernel(const __bf16* __restrict__ Y, const int* __restrict__ route_pos,
                               const float2* __restrict__ g01, float* __restrict__ out) {
  int gid = blockIdx.x * blockDim.x + threadIdx.x;
  int t = gid >> 6, c = (gid & 63) << 2;
  if (t >= NTOK) return;
  int p0 = route_pos[2 * t], p1 = route_pos[2 * t + 1];
  float2 g = g01[t];
  bf16x4 y0 = *(const bf16x4*)&Y[(size_t)p0 * DOUT + c];
  bf16x4 y1 = *(const bf16x4*)&Y[(size_t)p1 * DOUT + c];
  float4 o;
  o.x = g.x * (float)y0[0] + g.y * (float)y1[0];
  o.y = g.x * (float)y0[1] + g.y * (float)y1[1];
  o.z = g.x * (float)y0[2] + g.y * (float)y1[2];
  o.w = g.x * (float)y0[3] + g.y * (float)y1[3];
  *(float4*)&out[(size_t)t * DOUT + c] = o;
}

// ---------------- launcher ----------------
extern "C" void kernel_launch(void* const* d_in, const int* in_sizes, int n_in,
                              void* d_out, int out_size, void* d_ws, size_t ws_size,
                              hipStream_t stream) {
  const float* x          = (const float*)d_in[0];
  const float* gate_w     = (const float*)d_in[1];
  const float* gate_b     = (const float*)d_in[2];
  const float* gate_out_w = (const float*)d_in[3];
  const float* gate_out_b = (const float*)d_in[4];
  const float* w1         = (const float*)d_in[5];
  const float* b1         = (const float*)d_in[6];
  const float* w2         = (const float*)d_in[7];
  const float* b2         = (const float*)d_in[8];
  const float* w3         = (const float*)d_in[9];
  const float* b3         = (const float*)d_in[10];
  float* out = (float*)d_out;

  char* ws = (char*)d_ws;
  size_t o = 0;
  auto alloc = [&](size_t bytes) -> void* {
    o = (o + 255) & ~(size_t)255;
    void* p = ws + o;
    o += bytes;
    return p;
  };

  __bf16* w1t  = (__bf16*)alloc((size_t)NEXP * HID * DIN * 2);
  __bf16* w2t  = (__bf16*)alloc((size_t)NEXP * HID * HID * 2);
  __bf16* w3t  = (__bf16*)alloc((size_t)NEXP * DOUT * HID * 2);
  __bf16* gwt  = (__bf16*)alloc((size_t)HID * GK * 2);
  __bf16* H1   = (__bf16*)alloc((size_t)(NKA + 128) * HID * 2);
  // xs (gate split input + GEMM1 hi input; dead after GEMM1) aliases H2
  size_t r3 = (size_t)NTOK * GK * 2;
  size_t r4 = (size_t)(NKA + 128) * HID * 2;
  void* region2 = alloc(r3 > r4 ? r3 : r4);
  __bf16* xs = (__bf16*)region2;
  __bf16* H2 = (__bf16*)region2;
  float* logits    = (float*)alloc((size_t)NTOK * 16 * 4);
  int2*  e01       = (int2*)alloc((size_t)NTOK * 8);
  float2* g01      = (float2*)alloc((size_t)NTOK * 8);
  int*   offsets   = (int*)alloc((NEXP + 1) * 4);
  int*   blockhist = (int*)alloc((size_t)NBLK * NEXP * 4);
  int*   lrank     = (int*)alloc((size_t)NTOK * 2 * 4);
  int*   tok_sorted= (int*)alloc((size_t)(NKA + 128) * 4);
  int*   route_pos = (int*)alloc((size_t)NTOK * 2 * 4);
  int*   tile_e    = (int*)alloc(MAXTILE * 4);
  int*   tile_mt   = (int*)alloc(MAXTILE * 4);
  int*   ntiles    = (int*)alloc(4);
  __bf16* Y        = (__bf16*)alloc((size_t)(NKA + 128) * DOUT * 2);
  (void)ws_size; (void)n_in; (void)in_sizes; (void)out_size;

  // 1. prep (x split + gate weight split + zero(logits))
  prep_kernel<<<2304, 256, 0, stream>>>(x, xs, gate_w, gwt, logits);

  // 2. gate GEMM (BK=64) + fused logits epilogue, with weight transposes riding along
  gate_fused_kernel<<<8704, 256, 0, stream>>>(xs, gwt, gate_b, logits, gate_out_w,
                                              w1, w1t, w2, w2t, w3, w3t);

  // 3-4. top-2 routing, then fill+scan
  top2_kernel<<<NBLK, 256, 0, stream>>>(logits, gate_out_b, e01, g01, lrank, blockhist);
  fillscan_kernel<<<NBLK, 256, 0, stream>>>(e01, lrank, blockhist, tok_sorted, route_pos,
                                            offsets, tile_e, tile_mt, ntiles);

  // 5-7. expert GEMMs (BK=64; GEMM1 reads the hi block of xs via LDA=GK)
  moe_gemm_kernel<true><<<dim3(MAXTILE, HID / 128), 256, 0, stream>>>(
      xs, w1t, b1, H1, offsets, tok_sorted, tile_e, tile_mt, ntiles, GK, DIN, HID);
  moe_gemm_kernel<true><<<dim3(MAXTILE, HID / 128), 256, 0, stream>>>(
      H1, w2t, b2, H2, offsets, nullptr, tile_e, tile_mt, ntiles, HID, HID, HID);
  moe_gemm_kernel<false><<<dim3(MAXTILE, DOUT / 128), 256, 0, stream>>>(
      H2, w3t, b3, Y, offsets, nullptr, tile_e, tile_mt, ntiles, HID, HID, DOUT);

  // 8. combine (bf16 Y)
  combine_kernel<<<(NTOK * 64) / 256, 256, 0, stream>>>(Y, route_pos, g01, out);
}